// Round 1
// baseline (30787.872 us; speedup 1.0000x reference)
//
#include <hip/hip_runtime.h>
#include <stdint.h>

// ---------------------------------------------------------------------------
// HeteroGraphSAGE encoder, MI355X round 1 (f32, CSR-sorted aggregation).
//
// Strategy:
//  - Build CSR (sorted-by-dst edge lists) for the 4 (edge-type, direction)
//    aggregations once per launch: histogram + 3-phase exclusive scan +
//    atomic-cursor scatter. No float atomics anywhere.
//  - mean-aggregation: one 32-lane group per dst node, float4 accumulate.
//  - Linearity trick: transform features on the cheaper side of each sage:
//      rates   (u->m): aggregate raw hu to movies (50k dst), then @Wn0
//      tag_of  (t->m): transform ht (20k) first, aggregate transformed
//      rev_rates(m->u): transform hm (50k) first, aggregate transformed
//      has_tag (m->t): aggregate raw hm to tags (20k dst), then @Wn2
//  - Movie fc_self pair combined: Wc = Ws0+Ws3, bc = b0+b3.
//  - Layer-2 tag update skipped (dead). Final epilogues write to d_out.
//  - f32 register-tiled GEMM: block = 256 thr, tile 32 rows x 128 cols,
//    4x4 micro-tile, LDS-staged transposed X (32x36) and W (32x132) chunks.
// WS budget ~= 212 MB (floats ~200 MB + ints ~12 MB). d_out movie region is
// reused as scratch for agg_mu before the final movie epilogue (row-local
// in-place, safe).
// ---------------------------------------------------------------------------

#define NUSR 200000
#define NMOV 50000
#define NTAG 20000
#define FDIM 64
#define HDIM 128
#define NE1  800000
#define NE2  400000

static inline int cdiv(int a, int b) { return (a + b - 1) / b; }

// ---------------------------------------------------------------------------
// CSR build kernels
// ---------------------------------------------------------------------------
__global__ __launch_bounds__(256) void hist_kernel(const int* __restrict__ d, int n,
                                                   int* __restrict__ cnt) {
    int i = blockIdx.x * 256 + threadIdx.x;
    if (i < n) atomicAdd(&cnt[d[i]], 1);
}

__global__ __launch_bounds__(256) void scatter_kernel(const int* __restrict__ d,
                                                      const int* __restrict__ s, int n,
                                                      int* __restrict__ cur,
                                                      int* __restrict__ ss) {
    int i = blockIdx.x * 256 + threadIdx.x;
    if (i < n) {
        int p = atomicAdd(&cur[d[i]], 1);
        ss[p] = s[i];
    }
}

// exclusive scan of cnt[n] -> rowptr[n] (+ rowptr[n] = total), 1024 items/block
__global__ __launch_bounds__(256) void scan_p1(const int* __restrict__ cnt, int n,
                                               int* __restrict__ bsum) {
    __shared__ int sh[256];
    const int t = threadIdx.x;
    const int base = blockIdx.x * 1024 + t * 4;
    int s = 0;
#pragma unroll
    for (int i = 0; i < 4; i++) {
        int idx = base + i;
        if (idx < n) s += cnt[idx];
    }
    sh[t] = s;
    __syncthreads();
    for (int off = 128; off > 0; off >>= 1) {
        if (t < off) sh[t] += sh[t + off];
        __syncthreads();
    }
    if (t == 0) bsum[blockIdx.x] = sh[0];
}

__global__ __launch_bounds__(1024) void scan_p2(int* __restrict__ bsum, int nb,
                                                int* __restrict__ total_out) {
    __shared__ int sh[1024];
    const int t = threadIdx.x;
    int v = (t < nb) ? bsum[t] : 0;
    sh[t] = v;
    __syncthreads();
    for (int off = 1; off < 1024; off <<= 1) {
        int add = (t >= off) ? sh[t - off] : 0;
        __syncthreads();
        sh[t] += add;
        __syncthreads();
    }
    if (t < nb) bsum[t] = sh[t] - v;  // exclusive
    if (t == 1023) *total_out = sh[1023];
}

__global__ __launch_bounds__(256) void scan_p3(const int* __restrict__ cnt, int n,
                                               const int* __restrict__ bsum,
                                               int* __restrict__ rowptr) {
    __shared__ int sh[256];
    const int t = threadIdx.x;
    const int base = blockIdx.x * 1024 + t * 4;
    int v[4];
    int s = 0;
#pragma unroll
    for (int i = 0; i < 4; i++) {
        int idx = base + i;
        v[i] = (idx < n) ? cnt[idx] : 0;
        s += v[i];
    }
    sh[t] = s;
    __syncthreads();
    const int mine = s;
    for (int off = 1; off < 256; off <<= 1) {
        int add = (t >= off) ? sh[t - off] : 0;
        __syncthreads();
        sh[t] += add;
        __syncthreads();
    }
    int run = bsum[blockIdx.x] + sh[t] - mine;
#pragma unroll
    for (int i = 0; i < 4; i++) {
        int idx = base + i;
        if (idx < n) rowptr[idx] = run;
        run += v[i];
    }
}

// ---------------------------------------------------------------------------
// mean aggregation: one 32-lane group per dst row, float4 lanes (512B/row)
// ---------------------------------------------------------------------------
__global__ __launch_bounds__(256) void agg_mean(const float* __restrict__ feat,
                                                const int* __restrict__ srcs,
                                                const int* __restrict__ rowptr, int n_dst,
                                                float* __restrict__ out) {
    const int g = blockIdx.x * 8 + (threadIdx.x >> 5);
    const int lane = threadIdx.x & 31;
    if (g >= n_dst) return;
    const int s = rowptr[g];
    const int e = rowptr[g + 1];
    float a0 = 0.f, a1 = 0.f, a2 = 0.f, a3 = 0.f;
    for (int j = s; j < e; ++j) {
        const int src = srcs[j];
        const float4 v = *(const float4*)&feat[(size_t)src * HDIM + (lane << 2)];
        a0 += v.x; a1 += v.y; a2 += v.z; a3 += v.w;
    }
    const float sc = (e > s) ? 1.0f / (float)(e - s) : 0.0f;
    float4 o;
    o.x = a0 * sc; o.y = a1 * sc; o.z = a2 * sc; o.w = a3 * sc;
    *(float4*)&out[(size_t)g * HDIM + (lane << 2)] = o;
}

// ---------------------------------------------------------------------------
// fused f32 GEMM: out[i,:] = act( sum_m Xm[i,:] @ Wm.T + bias + add[i,:] )
// N = 128 cols always; K = 64 or 128. Tile 32 rows x 128 cols per block.
// ---------------------------------------------------------------------------
template <int K, int NMAT, bool HAS_ADD, bool HAS_BIAS, bool LEAKY>
__global__ __launch_bounds__(256) void gemm_fused(
    const float* __restrict__ X1, const float* __restrict__ W1,
    const float* __restrict__ X2, const float* __restrict__ W2,
    const float* __restrict__ addv, const float* __restrict__ bias,
    float* __restrict__ out, int n) {
    __shared__ float sX[32][36];    // [k][row], padded
    __shared__ float sW[32][132];   // [k][col], padded (16B-aligned stride)
    const int tid = threadIdx.x;
    const int row0 = blockIdx.x * 32;
    const int tx = tid & 31;   // col group -> cols 4*tx..
    const int ty = tid >> 5;   // row group -> rows 4*ty..
    float acc[4][4];
#pragma unroll
    for (int i = 0; i < 4; i++)
#pragma unroll
        for (int j = 0; j < 4; j++) acc[i][j] = 0.f;

#pragma unroll
    for (int mat = 0; mat < NMAT; ++mat) {
        const float* __restrict__ X = (mat == 0) ? X1 : X2;
        const float* __restrict__ W = (mat == 0) ? W1 : W2;
#pragma unroll
        for (int kb = 0; kb < K; kb += 32) {
            {   // stage X tile (32 rows x 32 k) transposed
                const int r = tid >> 3;
                const int k4 = (tid & 7) << 2;
                int gr = row0 + r;
                if (gr > n - 1) gr = n - 1;
                const float4 v = *(const float4*)&X[(size_t)gr * K + kb + k4];
                sX[k4 + 0][r] = v.x; sX[k4 + 1][r] = v.y;
                sX[k4 + 2][r] = v.z; sX[k4 + 3][r] = v.w;
            }
            {   // stage W tile (128 cols x 32 k) transposed
                const int c = tid >> 1;
                const int k0 = (tid & 1) << 4;
                const float* wp = &W[(size_t)c * K + kb + k0];
#pragma unroll
                for (int q = 0; q < 4; q++) {
                    const float4 v = *(const float4*)&wp[q * 4];
                    sW[k0 + q * 4 + 0][c] = v.x; sW[k0 + q * 4 + 1][c] = v.y;
                    sW[k0 + q * 4 + 2][c] = v.z; sW[k0 + q * 4 + 3][c] = v.w;
                }
            }
            __syncthreads();
#pragma unroll
            for (int kk = 0; kk < 32; ++kk) {
                float xr[4], wr[4];
                *(float4*)xr = *(const float4*)&sX[kk][ty << 2];
                *(float4*)wr = *(const float4*)&sW[kk][tx << 2];
#pragma unroll
                for (int i = 0; i < 4; i++)
#pragma unroll
                    for (int j = 0; j < 4; j++)
                        acc[i][j] = fmaf(xr[i], wr[j], acc[i][j]);
            }
            __syncthreads();
        }
    }
    // epilogue
    const int col = tx << 2;
    float bv[4] = {0.f, 0.f, 0.f, 0.f};
    if (HAS_BIAS) *(float4*)bv = *(const float4*)&bias[col];
#pragma unroll
    for (int i = 0; i < 4; i++) {
        const int r = row0 + (ty << 2) + i;
        if (r < n) {
            float o[4];
#pragma unroll
            for (int j = 0; j < 4; j++) o[j] = acc[i][j] + bv[j];
            if (HAS_ADD) {
                float a[4];
                *(float4*)a = *(const float4*)&addv[(size_t)r * HDIM + col];
#pragma unroll
                for (int j = 0; j < 4; j++) o[j] += a[j];
            }
            if (LEAKY) {
#pragma unroll
                for (int j = 0; j < 4; j++) o[j] = o[j] > 0.f ? o[j] : 0.1f * o[j];
            }
            *(float4*)&out[(size_t)r * HDIM + col] = *(float4*)o;
        }
    }
}

__global__ __launch_bounds__(256) void add_vec(const float* __restrict__ a,
                                               const float* __restrict__ b,
                                               float* __restrict__ c, int n) {
    int i = blockIdx.x * 256 + threadIdx.x;
    if (i < n) c[i] = a[i] + b[i];
}

// ---------------------------------------------------------------------------
static void build_csr(const int* dst, const int* src, int E, int ndst, int* rowptr,
                      int* sorted, int* cur, int* bsum, hipStream_t st) {
    hipMemsetAsync(cur, 0, (size_t)ndst * sizeof(int), st);
    hist_kernel<<<cdiv(E, 256), 256, 0, st>>>(dst, E, cur);
    const int nb = cdiv(ndst, 1024);
    scan_p1<<<nb, 256, 0, st>>>(cur, ndst, bsum);
    scan_p2<<<1, 1024, 0, st>>>(bsum, nb, rowptr + ndst);
    scan_p3<<<nb, 256, 0, st>>>(cur, ndst, bsum, rowptr);
    hipMemcpyAsync(cur, rowptr, (size_t)ndst * sizeof(int), hipMemcpyDeviceToDevice, st);
    scatter_kernel<<<cdiv(E, 256), 256, 0, st>>>(dst, src, E, cur, sorted);
}

extern "C" void kernel_launch(void* const* d_in, const int* in_sizes, int n_in,
                              void* d_out, int out_size, void* d_ws, size_t ws_size,
                              hipStream_t stream) {
    const float* genre    = (const float*)d_in[0];
    const float* user_emb = (const float*)d_in[1];
    const float* tag_emb  = (const float*)d_in[2];
    const float* movie_W  = (const float*)d_in[3];
    const float* movie_b  = (const float*)d_in[4];
    const float* Wn       = (const float*)d_in[5];
    const float* Wsf      = (const float*)d_in[6];
    const float* bsf      = (const float*)d_in[7];
    const int* rates_u    = (const int*)d_in[8];
    const int* rates_m    = (const int*)d_in[9];
    const int* tag_m      = (const int*)d_in[10];
    const int* tag_t      = (const int*)d_in[11];

    float* out_u = (float*)d_out;                      // NUSR x H
    float* out_m = out_u + (size_t)NUSR * HDIM;        // NMOV x H

    // ---- workspace carve-up ----
    char* w = (char*)d_ws;
    auto alloc = [&](size_t bytes) -> char* {
        char* p = w;
        w += (bytes + 511) & ~(size_t)511;
        return p;
    };
    float* hm0 = (float*)alloc((size_t)NMOV * HDIM * 4);  // hm layer-0 input; L2 agg_mt
    float* U1  = (float*)alloc((size_t)NUSR * HDIM * 4);  // agg_u L1 -> hu1
    float* M2  = (float*)alloc((size_t)NMOV * HDIM * 4);  // agg_mt L1 -> hm1
    float* M3  = (float*)alloc((size_t)NMOV * HDIM * 4);  // tmp_m (pre-transform)
    float* T1  = (float*)alloc((size_t)NTAG * HDIM * 4);  // tmp_t (pre-transform)
    float* T2  = (float*)alloc((size_t)NTAG * HDIM * 4);  // agg_t L1 -> ht1
    float* Wc  = (float*)alloc((size_t)HDIM * HDIM * 4);  // combined movie self W
    float* bc  = (float*)alloc((size_t)HDIM * 4);
    int* rp_rm = (int*)alloc((size_t)(NMOV + 1) * 4);
    int* ss_rm = (int*)alloc((size_t)NE1 * 4);
    int* rp_ru = (int*)alloc((size_t)(NUSR + 1) * 4);
    int* ss_ru = (int*)alloc((size_t)NE1 * 4);
    int* rp_tm = (int*)alloc((size_t)(NMOV + 1) * 4);
    int* ss_tm = (int*)alloc((size_t)NE2 * 4);
    int* rp_tt = (int*)alloc((size_t)(NTAG + 1) * 4);
    int* ss_tt = (int*)alloc((size_t)NE2 * 4);
    int* cur   = (int*)alloc((size_t)NUSR * 4);
    int* bsum  = (int*)alloc((size_t)1024 * 4);
    float* M1  = out_m;  // d_out movie region doubles as agg_mu scratch

    // ---- CSR for the 4 aggregations (reused by both layers) ----
    build_csr(rates_m, rates_u, NE1, NMOV, rp_rm, ss_rm, cur, bsum, stream);  // rates u->m
    build_csr(rates_u, rates_m, NE1, NUSR, rp_ru, ss_ru, cur, bsum, stream);  // rev m->u
    build_csr(tag_m, tag_t, NE2, NMOV, rp_tm, ss_tm, cur, bsum, stream);      // tag_of t->m
    build_csr(tag_t, tag_m, NE2, NTAG, rp_tt, ss_tt, cur, bsum, stream);      // has_tag m->t

    const size_t WHH = (size_t)HDIM * HDIM;

    // hm0 = genre @ movie_W.T + movie_b
    gemm_fused<FDIM, 1, false, true, false><<<cdiv(NMOV, 32), 256, 0, stream>>>(
        genre, movie_W, nullptr, nullptr, nullptr, movie_b, hm0, NMOV);

    // ================= layer 0 =================
    add_vec<<<cdiv((int)WHH, 256), 256, 0, stream>>>(Wsf + 0 * WHH, Wsf + 3 * WHH, Wc, (int)WHH);
    add_vec<<<1, 256, 0, stream>>>(bsf + 0 * HDIM, bsf + 3 * HDIM, bc, HDIM);
    // pre-transforms (linearity trick)
    gemm_fused<HDIM, 1, false, false, false><<<cdiv(NMOV, 32), 256, 0, stream>>>(
        hm0, Wn + 1 * WHH, nullptr, nullptr, nullptr, nullptr, M3, NMOV);  // tmp_m = hm0 @ Wn[0,1].T
    gemm_fused<HDIM, 1, false, false, false><<<cdiv(NTAG, 32), 256, 0, stream>>>(
        tag_emb, Wn + 3 * WHH, nullptr, nullptr, nullptr, nullptr, T1, NTAG);  // tmp_t = ht0 @ Wn[0,3].T
    // aggregations (means)
    agg_mean<<<cdiv(NUSR, 8), 256, 0, stream>>>(M3, ss_ru, rp_ru, NUSR, U1);        // -> users
    agg_mean<<<cdiv(NMOV, 8), 256, 0, stream>>>(user_emb, ss_rm, rp_rm, NMOV, M1);  // raw hu -> movies
    agg_mean<<<cdiv(NMOV, 8), 256, 0, stream>>>(T1, ss_tm, rp_tm, NMOV, M2);        // -> movies
    agg_mean<<<cdiv(NTAG, 8), 256, 0, stream>>>(hm0, ss_tt, rp_tt, NTAG, T2);       // raw hm -> tags
    // updates
    gemm_fused<HDIM, 1, true, true, true><<<cdiv(NUSR, 32), 256, 0, stream>>>(
        user_emb, Wsf + 1 * WHH, nullptr, nullptr, U1, bsf + 1 * HDIM, U1, NUSR);   // hu1
    gemm_fused<HDIM, 2, true, true, true><<<cdiv(NMOV, 32), 256, 0, stream>>>(
        hm0, Wc, M1, Wn + 0 * WHH, M2, bc, M2, NMOV);                               // hm1
    gemm_fused<HDIM, 2, false, true, true><<<cdiv(NTAG, 32), 256, 0, stream>>>(
        tag_emb, Wsf + 2 * WHH, T2, Wn + 2 * WHH, nullptr, bsf + 2 * HDIM, T2, NTAG);  // ht1

    // ================= layer 1 (tag update dead; outputs -> d_out) =================
    const float* Wn1 = Wn + 4 * WHH;
    const float* Ws1 = Wsf + 4 * WHH;
    const float* bs1 = bsf + 4 * HDIM;
    add_vec<<<cdiv((int)WHH, 256), 256, 0, stream>>>(Ws1 + 0 * WHH, Ws1 + 3 * WHH, Wc, (int)WHH);
    add_vec<<<1, 256, 0, stream>>>(bs1 + 0 * HDIM, bs1 + 3 * HDIM, bc, HDIM);
    gemm_fused<HDIM, 1, false, false, false><<<cdiv(NMOV, 32), 256, 0, stream>>>(
        M2, Wn1 + 1 * WHH, nullptr, nullptr, nullptr, nullptr, M3, NMOV);  // tmp_m = hm1 @ Wn[1,1].T
    gemm_fused<HDIM, 1, false, false, false><<<cdiv(NTAG, 32), 256, 0, stream>>>(
        T2, Wn1 + 3 * WHH, nullptr, nullptr, nullptr, nullptr, T1, NTAG);  // tmp_t = ht1 @ Wn[1,3].T
    agg_mean<<<cdiv(NUSR, 8), 256, 0, stream>>>(M3, ss_ru, rp_ru, NUSR, out_u);  // -> users (into d_out)
    agg_mean<<<cdiv(NMOV, 8), 256, 0, stream>>>(U1, ss_rm, rp_rm, NMOV, M1);     // raw hu1 -> movies
    agg_mean<<<cdiv(NMOV, 8), 256, 0, stream>>>(T1, ss_tm, rp_tm, NMOV, hm0);    // -> movies (hm0 buf free)
    gemm_fused<HDIM, 1, true, true, true><<<cdiv(NUSR, 32), 256, 0, stream>>>(
        U1, Ws1 + 1 * WHH, nullptr, nullptr, out_u, bs1 + 1 * HDIM, out_u, NUSR);  // final hu
    gemm_fused<HDIM, 2, true, true, true><<<cdiv(NMOV, 32), 256, 0, stream>>>(
        M2, Wc, M1, Wn1 + 0 * WHH, hm0, bc, out_m, NMOV);                          // final hm
}

// Round 2
// 1203.792 us; speedup vs baseline: 25.5757x; 25.5757x over previous
//
#include <hip/hip_runtime.h>
#include <stdint.h>

// ---------------------------------------------------------------------------
// HeteroGraphSAGE encoder, MI355X round 2.
// Round-1 post-mortem: gemm_fused spilled (full unroll of mat+kb loops ->
// >256 live VGPRs -> scratch traffic 18.5 GB/dispatch, 6 ms). Fix: 128x128
// block tile, 8x8 micro-tile, `#pragma unroll 1` on the K-chunk loop,
// bounded kk unroll. Everything else (CSR aggregation, linearity tricks,
// dead-code elimination) unchanged from round 1.
// ---------------------------------------------------------------------------

#define NUSR 200000
#define NMOV 50000
#define NTAG 20000
#define FDIM 64
#define HDIM 128
#define NE1  800000
#define NE2  400000

static inline int cdiv(int a, int b) { return (a + b - 1) / b; }

// ---------------------------------------------------------------------------
// CSR build kernels
// ---------------------------------------------------------------------------
__global__ __launch_bounds__(256) void hist_kernel(const int* __restrict__ d, int n,
                                                   int* __restrict__ cnt) {
    int i = blockIdx.x * 256 + threadIdx.x;
    if (i < n) atomicAdd(&cnt[d[i]], 1);
}

__global__ __launch_bounds__(256) void scatter_kernel(const int* __restrict__ d,
                                                      const int* __restrict__ s, int n,
                                                      int* __restrict__ cur,
                                                      int* __restrict__ ss) {
    int i = blockIdx.x * 256 + threadIdx.x;
    if (i < n) {
        int p = atomicAdd(&cur[d[i]], 1);
        ss[p] = s[i];
    }
}

// exclusive scan of cnt[n] -> rowptr[n] (+ rowptr[n] = total), 1024 items/block
__global__ __launch_bounds__(256) void scan_p1(const int* __restrict__ cnt, int n,
                                               int* __restrict__ bsum) {
    __shared__ int sh[256];
    const int t = threadIdx.x;
    const int base = blockIdx.x * 1024 + t * 4;
    int s = 0;
#pragma unroll
    for (int i = 0; i < 4; i++) {
        int idx = base + i;
        if (idx < n) s += cnt[idx];
    }
    sh[t] = s;
    __syncthreads();
    for (int off = 128; off > 0; off >>= 1) {
        if (t < off) sh[t] += sh[t + off];
        __syncthreads();
    }
    if (t == 0) bsum[blockIdx.x] = sh[0];
}

__global__ __launch_bounds__(1024) void scan_p2(int* __restrict__ bsum, int nb,
                                                int* __restrict__ total_out) {
    __shared__ int sh[1024];
    const int t = threadIdx.x;
    int v = (t < nb) ? bsum[t] : 0;
    sh[t] = v;
    __syncthreads();
    for (int off = 1; off < 1024; off <<= 1) {
        int add = (t >= off) ? sh[t - off] : 0;
        __syncthreads();
        sh[t] += add;
        __syncthreads();
    }
    if (t < nb) bsum[t] = sh[t] - v;  // exclusive
    if (t == 1023) *total_out = sh[1023];
}

__global__ __launch_bounds__(256) void scan_p3(const int* __restrict__ cnt, int n,
                                               const int* __restrict__ bsum,
                                               int* __restrict__ rowptr) {
    __shared__ int sh[256];
    const int t = threadIdx.x;
    const int base = blockIdx.x * 1024 + t * 4;
    int v[4];
    int s = 0;
#pragma unroll
    for (int i = 0; i < 4; i++) {
        int idx = base + i;
        v[i] = (idx < n) ? cnt[idx] : 0;
        s += v[i];
    }
    sh[t] = s;
    __syncthreads();
    const int mine = s;
    for (int off = 1; off < 256; off <<= 1) {
        int add = (t >= off) ? sh[t - off] : 0;
        __syncthreads();
        sh[t] += add;
        __syncthreads();
    }
    int run = bsum[blockIdx.x] + sh[t] - mine;
#pragma unroll
    for (int i = 0; i < 4; i++) {
        int idx = base + i;
        if (idx < n) rowptr[idx] = run;
        run += v[i];
    }
}

// ---------------------------------------------------------------------------
// mean aggregation: one 32-lane group per dst row, float4 lanes (512B/row)
// ---------------------------------------------------------------------------
__global__ __launch_bounds__(256) void agg_mean(const float* __restrict__ feat,
                                                const int* __restrict__ srcs,
                                                const int* __restrict__ rowptr, int n_dst,
                                                float* __restrict__ out) {
    const int g = blockIdx.x * 8 + (threadIdx.x >> 5);
    const int lane = threadIdx.x & 31;
    if (g >= n_dst) return;
    const int s = rowptr[g];
    const int e = rowptr[g + 1];
    float a0 = 0.f, a1 = 0.f, a2 = 0.f, a3 = 0.f;
    for (int j = s; j < e; ++j) {
        const int src = srcs[j];
        const float4 v = *(const float4*)&feat[(size_t)src * HDIM + (lane << 2)];
        a0 += v.x; a1 += v.y; a2 += v.z; a3 += v.w;
    }
    const float sc = (e > s) ? 1.0f / (float)(e - s) : 0.0f;
    float4 o;
    o.x = a0 * sc; o.y = a1 * sc; o.z = a2 * sc; o.w = a3 * sc;
    *(float4*)&out[(size_t)g * HDIM + (lane << 2)] = o;
}

// ---------------------------------------------------------------------------
// fused f32 GEMM: out[i,:] = act( sum_m Xm[i,:] @ Wm.T + bias + add[i,:] )
// N = 128 cols always; K = 64 or 128. Tile 128 rows x 128 cols per block,
// 8x8 micro-tile per thread (64 acc VGPRs). K-chunk loop NOT unrolled
// (spill avoidance — round-1 lesson), kk unrolled by 4.
// ---------------------------------------------------------------------------
template <int K, int NMAT, bool HAS_ADD, bool HAS_BIAS, bool LEAKY>
__global__ __launch_bounds__(256) void gemm_fused(
    const float* __restrict__ X1, const float* __restrict__ W1,
    const float* __restrict__ X2, const float* __restrict__ W2,
    const float* __restrict__ addv, const float* __restrict__ bias,
    float* __restrict__ out, int n) {
    __shared__ float sX[32][132];   // [k][row], padded
    __shared__ float sW[32][132];   // [k][col], padded
    const int tid = threadIdx.x;
    const int tx = tid & 15;        // col group -> cols 8*tx..
    const int ty = tid >> 4;        // row group -> rows 8*ty..
    const int row0 = blockIdx.x * 128;
    float acc[8][8];
#pragma unroll
    for (int i = 0; i < 8; i++)
#pragma unroll
        for (int j = 0; j < 8; j++) acc[i][j] = 0.f;

    for (int mat = 0; mat < NMAT; ++mat) {
        const float* __restrict__ X = (mat == 0) ? X1 : X2;
        const float* __restrict__ W = (mat == 0) ? W1 : W2;
#pragma unroll 1
        for (int kb = 0; kb < K; kb += 32) {
            {   // stage X tile (128 rows x 32 k) transposed: thread -> 1 row, 16 k
                const int r = tid >> 1;
                const int k0 = (tid & 1) << 4;
                int gr = row0 + r;
                if (gr >= n) gr = n - 1;
                const float* xp = &X[(size_t)gr * K + kb + k0];
#pragma unroll
                for (int q = 0; q < 4; ++q) {
                    const float4 v = *(const float4*)&xp[q * 4];
                    sX[k0 + q * 4 + 0][r] = v.x;
                    sX[k0 + q * 4 + 1][r] = v.y;
                    sX[k0 + q * 4 + 2][r] = v.z;
                    sX[k0 + q * 4 + 3][r] = v.w;
                }
            }
            {   // stage W tile (128 cols x 32 k) transposed
                const int c = tid >> 1;
                const int k0 = (tid & 1) << 4;
                const float* wp = &W[(size_t)c * K + kb + k0];
#pragma unroll
                for (int q = 0; q < 4; ++q) {
                    const float4 v = *(const float4*)&wp[q * 4];
                    sW[k0 + q * 4 + 0][c] = v.x;
                    sW[k0 + q * 4 + 1][c] = v.y;
                    sW[k0 + q * 4 + 2][c] = v.z;
                    sW[k0 + q * 4 + 3][c] = v.w;
                }
            }
            __syncthreads();
#pragma unroll 4
            for (int kk = 0; kk < 32; ++kk) {
                float xr[8], wr[8];
                *(float4*)&xr[0] = *(const float4*)&sX[kk][ty << 3];
                *(float4*)&xr[4] = *(const float4*)&sX[kk][(ty << 3) + 4];
                *(float4*)&wr[0] = *(const float4*)&sW[kk][tx << 3];
                *(float4*)&wr[4] = *(const float4*)&sW[kk][(tx << 3) + 4];
#pragma unroll
                for (int i = 0; i < 8; i++)
#pragma unroll
                    for (int j = 0; j < 8; j++)
                        acc[i][j] = fmaf(xr[i], wr[j], acc[i][j]);
            }
            __syncthreads();
        }
    }
    // epilogue
    const int col = tx << 3;
    float bv[8] = {0.f, 0.f, 0.f, 0.f, 0.f, 0.f, 0.f, 0.f};
    if (HAS_BIAS) {
        *(float4*)&bv[0] = *(const float4*)&bias[col];
        *(float4*)&bv[4] = *(const float4*)&bias[col + 4];
    }
#pragma unroll
    for (int i = 0; i < 8; i++) {
        const int r = row0 + (ty << 3) + i;
        if (r < n) {
            float o[8];
#pragma unroll
            for (int j = 0; j < 8; j++) o[j] = acc[i][j] + bv[j];
            if (HAS_ADD) {
                float a[8];
                *(float4*)&a[0] = *(const float4*)&addv[(size_t)r * HDIM + col];
                *(float4*)&a[4] = *(const float4*)&addv[(size_t)r * HDIM + col + 4];
#pragma unroll
                for (int j = 0; j < 8; j++) o[j] += a[j];
            }
            if (LEAKY) {
#pragma unroll
                for (int j = 0; j < 8; j++) o[j] = o[j] > 0.f ? o[j] : 0.1f * o[j];
            }
            *(float4*)&out[(size_t)r * HDIM + col] = *(float4*)&o[0];
            *(float4*)&out[(size_t)r * HDIM + col + 4] = *(float4*)&o[4];
        }
    }
}

__global__ __launch_bounds__(256) void add_vec(const float* __restrict__ a,
                                               const float* __restrict__ b,
                                               float* __restrict__ c, int n) {
    int i = blockIdx.x * 256 + threadIdx.x;
    if (i < n) c[i] = a[i] + b[i];
}

// ---------------------------------------------------------------------------
static void build_csr(const int* dst, const int* src, int E, int ndst, int* rowptr,
                      int* sorted, int* cur, int* bsum, hipStream_t st) {
    hipMemsetAsync(cur, 0, (size_t)ndst * sizeof(int), st);
    hist_kernel<<<cdiv(E, 256), 256, 0, st>>>(dst, E, cur);
    const int nb = cdiv(ndst, 1024);
    scan_p1<<<nb, 256, 0, st>>>(cur, ndst, bsum);
    scan_p2<<<1, 1024, 0, st>>>(bsum, nb, rowptr + ndst);
    scan_p3<<<nb, 256, 0, st>>>(cur, ndst, bsum, rowptr);
    hipMemcpyAsync(cur, rowptr, (size_t)ndst * sizeof(int), hipMemcpyDeviceToDevice, st);
    scatter_kernel<<<cdiv(E, 256), 256, 0, st>>>(dst, src, E, cur, sorted);
}

extern "C" void kernel_launch(void* const* d_in, const int* in_sizes, int n_in,
                              void* d_out, int out_size, void* d_ws, size_t ws_size,
                              hipStream_t stream) {
    const float* genre    = (const float*)d_in[0];
    const float* user_emb = (const float*)d_in[1];
    const float* tag_emb  = (const float*)d_in[2];
    const float* movie_W  = (const float*)d_in[3];
    const float* movie_b  = (const float*)d_in[4];
    const float* Wn       = (const float*)d_in[5];
    const float* Wsf      = (const float*)d_in[6];
    const float* bsf      = (const float*)d_in[7];
    const int* rates_u    = (const int*)d_in[8];
    const int* rates_m    = (const int*)d_in[9];
    const int* tag_m      = (const int*)d_in[10];
    const int* tag_t      = (const int*)d_in[11];

    float* out_u = (float*)d_out;                      // NUSR x H
    float* out_m = out_u + (size_t)NUSR * HDIM;        // NMOV x H

    // ---- workspace carve-up ----
    char* w = (char*)d_ws;
    auto alloc = [&](size_t bytes) -> char* {
        char* p = w;
        w += (bytes + 511) & ~(size_t)511;
        return p;
    };
    float* hm0 = (float*)alloc((size_t)NMOV * HDIM * 4);  // hm layer-0 input; L2 agg_mt
    float* U1  = (float*)alloc((size_t)NUSR * HDIM * 4);  // agg_u L1 -> hu1
    float* M2  = (float*)alloc((size_t)NMOV * HDIM * 4);  // agg_mt L1 -> hm1
    float* M3  = (float*)alloc((size_t)NMOV * HDIM * 4);  // tmp_m (pre-transform)
    float* T1  = (float*)alloc((size_t)NTAG * HDIM * 4);  // tmp_t (pre-transform)
    float* T2  = (float*)alloc((size_t)NTAG * HDIM * 4);  // agg_t L1 -> ht1
    float* Wc  = (float*)alloc((size_t)HDIM * HDIM * 4);  // combined movie self W
    float* bc  = (float*)alloc((size_t)HDIM * 4);
    int* rp_rm = (int*)alloc((size_t)(NMOV + 1) * 4);
    int* ss_rm = (int*)alloc((size_t)NE1 * 4);
    int* rp_ru = (int*)alloc((size_t)(NUSR + 1) * 4);
    int* ss_ru = (int*)alloc((size_t)NE1 * 4);
    int* rp_tm = (int*)alloc((size_t)(NMOV + 1) * 4);
    int* ss_tm = (int*)alloc((size_t)NE2 * 4);
    int* rp_tt = (int*)alloc((size_t)(NTAG + 1) * 4);
    int* ss_tt = (int*)alloc((size_t)NE2 * 4);
    int* cur   = (int*)alloc((size_t)NUSR * 4);
    int* bsum  = (int*)alloc((size_t)1024 * 4);
    float* M1  = out_m;  // d_out movie region doubles as agg_mu scratch

    // ---- CSR for the 4 aggregations (reused by both layers) ----
    build_csr(rates_m, rates_u, NE1, NMOV, rp_rm, ss_rm, cur, bsum, stream);  // rates u->m
    build_csr(rates_u, rates_m, NE1, NUSR, rp_ru, ss_ru, cur, bsum, stream);  // rev m->u
    build_csr(tag_m, tag_t, NE2, NMOV, rp_tm, ss_tm, cur, bsum, stream);      // tag_of t->m
    build_csr(tag_t, tag_m, NE2, NTAG, rp_tt, ss_tt, cur, bsum, stream);      // has_tag m->t

    const size_t WHH = (size_t)HDIM * HDIM;

    // hm0 = genre @ movie_W.T + movie_b
    gemm_fused<FDIM, 1, false, true, false><<<cdiv(NMOV, 128), 256, 0, stream>>>(
        genre, movie_W, nullptr, nullptr, nullptr, movie_b, hm0, NMOV);

    // ================= layer 0 =================
    add_vec<<<cdiv((int)WHH, 256), 256, 0, stream>>>(Wsf + 0 * WHH, Wsf + 3 * WHH, Wc, (int)WHH);
    add_vec<<<1, 256, 0, stream>>>(bsf + 0 * HDIM, bsf + 3 * HDIM, bc, HDIM);
    // pre-transforms (linearity trick)
    gemm_fused<HDIM, 1, false, false, false><<<cdiv(NMOV, 128), 256, 0, stream>>>(
        hm0, Wn + 1 * WHH, nullptr, nullptr, nullptr, nullptr, M3, NMOV);  // tmp_m = hm0 @ Wn[0,1].T
    gemm_fused<HDIM, 1, false, false, false><<<cdiv(NTAG, 128), 256, 0, stream>>>(
        tag_emb, Wn + 3 * WHH, nullptr, nullptr, nullptr, nullptr, T1, NTAG);  // tmp_t = ht0 @ Wn[0,3].T
    // aggregations (means)
    agg_mean<<<cdiv(NUSR, 8), 256, 0, stream>>>(M3, ss_ru, rp_ru, NUSR, U1);        // -> users
    agg_mean<<<cdiv(NMOV, 8), 256, 0, stream>>>(user_emb, ss_rm, rp_rm, NMOV, M1);  // raw hu -> movies
    agg_mean<<<cdiv(NMOV, 8), 256, 0, stream>>>(T1, ss_tm, rp_tm, NMOV, M2);        // -> movies
    agg_mean<<<cdiv(NTAG, 8), 256, 0, stream>>>(hm0, ss_tt, rp_tt, NTAG, T2);       // raw hm -> tags
    // updates
    gemm_fused<HDIM, 1, true, true, true><<<cdiv(NUSR, 128), 256, 0, stream>>>(
        user_emb, Wsf + 1 * WHH, nullptr, nullptr, U1, bsf + 1 * HDIM, U1, NUSR);   // hu1
    gemm_fused<HDIM, 2, true, true, true><<<cdiv(NMOV, 128), 256, 0, stream>>>(
        hm0, Wc, M1, Wn + 0 * WHH, M2, bc, M2, NMOV);                               // hm1
    gemm_fused<HDIM, 2, false, true, true><<<cdiv(NTAG, 128), 256, 0, stream>>>(
        tag_emb, Wsf + 2 * WHH, T2, Wn + 2 * WHH, nullptr, bsf + 2 * HDIM, T2, NTAG);  // ht1

    // ================= layer 1 (tag update dead; outputs -> d_out) =================
    const float* Wn1 = Wn + 4 * WHH;
    const float* Ws1 = Wsf + 4 * WHH;
    const float* bs1 = bsf + 4 * HDIM;
    add_vec<<<cdiv((int)WHH, 256), 256, 0, stream>>>(Ws1 + 0 * WHH, Ws1 + 3 * WHH, Wc, (int)WHH);
    add_vec<<<1, 256, 0, stream>>>(bs1 + 0 * HDIM, bs1 + 3 * HDIM, bc, HDIM);
    gemm_fused<HDIM, 1, false, false, false><<<cdiv(NMOV, 128), 256, 0, stream>>>(
        M2, Wn1 + 1 * WHH, nullptr, nullptr, nullptr, nullptr, M3, NMOV);  // tmp_m = hm1 @ Wn[1,1].T
    gemm_fused<HDIM, 1, false, false, false><<<cdiv(NTAG, 128), 256, 0, stream>>>(
        T2, Wn1 + 3 * WHH, nullptr, nullptr, nullptr, nullptr, T1, NTAG);  // tmp_t = ht1 @ Wn[1,3].T
    agg_mean<<<cdiv(NUSR, 8), 256, 0, stream>>>(M3, ss_ru, rp_ru, NUSR, out_u);  // -> users (into d_out)
    agg_mean<<<cdiv(NMOV, 8), 256, 0, stream>>>(U1, ss_rm, rp_rm, NMOV, M1);     // raw hu1 -> movies
    agg_mean<<<cdiv(NMOV, 8), 256, 0, stream>>>(T1, ss_tm, rp_tm, NMOV, hm0);    // -> movies (hm0 buf free)
    gemm_fused<HDIM, 1, true, true, true><<<cdiv(NUSR, 128), 256, 0, stream>>>(
        U1, Ws1 + 1 * WHH, nullptr, nullptr, out_u, bs1 + 1 * HDIM, out_u, NUSR);  // final hu
    gemm_fused<HDIM, 2, true, true, true><<<cdiv(NMOV, 128), 256, 0, stream>>>(
        M2, Wc, M1, Wn1 + 0 * WHH, hm0, bc, out_m, NMOV);                          // final hm
}

// Round 3
// 994.280 us; speedup vs baseline: 30.9650x; 1.2107x over previous
//
#include <hip/hip_runtime.h>
#include <stdint.h>

// ---------------------------------------------------------------------------
// HeteroGraphSAGE encoder, MI355X round 3.
// Round-2 post-mortem: f32 VALU GEMM at 62 TF (VALUBusy 51%, 8M LDS-conflict
// cycles); aggs ~half the time. This round:
//   - bf16 MFMA GEMM (mfma_f32_16x16x32_bf16), LDS-free: A/B fragments are
//     contiguous 16B runs of row-major X and W (B^T form). f32 accumulate.
//   - all intermediate features stored bf16 (halves agg gather + GEMM bytes).
//   - CSR build fused: 1 histogram + 1 scan (concatenated counts) + 1 scatter.
//   - weights converted/combined in one prep kernel.
// ---------------------------------------------------------------------------

#define NUSR 200000
#define NMOV 50000
#define NTAG 20000
#define FDIM 64
#define HDIM 128
#define NE1  800000
#define NE2  400000

#define OFF_RM 0
#define OFF_RU (NMOV)
#define OFF_TM (NMOV + NUSR)
#define OFF_TT (NMOV + NUSR + NMOV)
#define NTOT   (2 * NMOV + NUSR + NTAG)      // 320000
#define ETOT   (2 * NE1 + 2 * NE2)           // 2.4M
#define WHH    (HDIM * HDIM)

typedef short bf16x8 __attribute__((ext_vector_type(8)));
typedef float f32x4 __attribute__((ext_vector_type(4)));

static inline int cdiv(int a, int b) { return (a + b - 1) / b; }

__device__ __forceinline__ float bf2f(unsigned short u) {
    union { unsigned int i; float f; } c;
    c.i = ((unsigned int)u) << 16;
    return c.f;
}
__device__ __forceinline__ unsigned short f2bf(float f) {
    union { float f; unsigned int i; } c;
    c.f = f;
    unsigned int i = c.i;
    return (unsigned short)((i + 0x7fffu + ((i >> 16) & 1u)) >> 16);  // RNE
}

// ---------------------------------------------------------------------------
// conversions / weight prep
// ---------------------------------------------------------------------------
__global__ __launch_bounds__(256) void cvt_bf16(const float* __restrict__ in,
                                                unsigned short* __restrict__ out, int n4) {
    int i = blockIdx.x * 256 + threadIdx.x;
    if (i < n4) {
        const float4 v = ((const float4*)in)[i];
        ushort4 o;
        o.x = f2bf(v.x); o.y = f2bf(v.y); o.z = f2bf(v.z); o.w = f2bf(v.w);
        ((ushort4*)out)[i] = o;
    }
}

// WB layout: [0,8192): movie_W.  Then per layer l (stride 7*WHH):
//   e=0..3: Wn[l,e]; e=4: Ws[l,1]; e=5: Ws[l,2]; e=6: Ws[l,0]+Ws[l,3].
// bcc[l*128+c] = bs[l,0,c]+bs[l,3,c].
__global__ __launch_bounds__(256) void prep_weights(const float* __restrict__ movie_W,
                                                    const float* __restrict__ Wn,
                                                    const float* __restrict__ Ws,
                                                    const float* __restrict__ bs,
                                                    unsigned short* __restrict__ WB,
                                                    float* __restrict__ bcc) {
    const int i = blockIdx.x * 256 + threadIdx.x;
    if (i < 256) {
        const int l = i >> 7, c = i & 127;
        bcc[i] = bs[(l * 4 + 0) * HDIM + c] + bs[(l * 4 + 3) * HDIM + c];
    }
    const int total = 8192 + 2 * 7 * WHH;
    if (i < total) {
        float v;
        if (i < 8192) {
            v = movie_W[i];
        } else {
            const int j = i - 8192;
            const int l = j / (7 * WHH);
            const int r = j % (7 * WHH);
            const int e = r / WHH;
            const int o = r % WHH;
            if (e < 4) v = Wn[(l * 4 + e) * WHH + o];
            else if (e == 4) v = Ws[(l * 4 + 1) * WHH + o];
            else if (e == 5) v = Ws[(l * 4 + 2) * WHH + o];
            else v = Ws[(l * 4 + 0) * WHH + o] + Ws[(l * 4 + 3) * WHH + o];
        }
        WB[i] = f2bf(v);
    }
}

// ---------------------------------------------------------------------------
// fused CSR build (all 4 edge-type/direction segments in one counts array)
// ---------------------------------------------------------------------------
__global__ __launch_bounds__(256) void hist_all(const int* __restrict__ ru,
                                                const int* __restrict__ rm,
                                                const int* __restrict__ tm,
                                                const int* __restrict__ tt,
                                                int* __restrict__ cnt) {
    const int i = blockIdx.x * 256 + threadIdx.x;
    if (i < NE1)                 atomicAdd(&cnt[OFF_RM + rm[i]], 1);
    else if (i < 2 * NE1)        atomicAdd(&cnt[OFF_RU + ru[i - NE1]], 1);
    else if (i < 2 * NE1 + NE2)  atomicAdd(&cnt[OFF_TM + tm[i - 2 * NE1]], 1);
    else if (i < ETOT)           atomicAdd(&cnt[OFF_TT + tt[i - 2 * NE1 - NE2]], 1);
}

__global__ __launch_bounds__(256) void scatter_all(const int* __restrict__ ru,
                                                   const int* __restrict__ rm,
                                                   const int* __restrict__ tm,
                                                   const int* __restrict__ tt,
                                                   int* __restrict__ cur,
                                                   int* __restrict__ sorted) {
    const int i = blockIdx.x * 256 + threadIdx.x;
    if (i < NE1) {
        const int p = atomicAdd(&cur[OFF_RM + rm[i]], 1); sorted[p] = ru[i];
    } else if (i < 2 * NE1) {
        const int e = i - NE1;
        const int p = atomicAdd(&cur[OFF_RU + ru[e]], 1); sorted[p] = rm[e];
    } else if (i < 2 * NE1 + NE2) {
        const int e = i - 2 * NE1;
        const int p = atomicAdd(&cur[OFF_TM + tm[e]], 1); sorted[p] = tt[e];
    } else if (i < ETOT) {
        const int e = i - 2 * NE1 - NE2;
        const int p = atomicAdd(&cur[OFF_TT + tt[e]], 1); sorted[p] = tm[e];
    }
}

// exclusive scan of cnt[n] -> rowptr[n] (+ rowptr[n]=total), 1024 items/block
__global__ __launch_bounds__(256) void scan_p1(const int* __restrict__ cnt, int n,
                                               int* __restrict__ bsum) {
    __shared__ int sh[256];
    const int t = threadIdx.x;
    const int base = blockIdx.x * 1024 + t * 4;
    int s = 0;
#pragma unroll
    for (int i = 0; i < 4; i++) {
        int idx = base + i;
        if (idx < n) s += cnt[idx];
    }
    sh[t] = s;
    __syncthreads();
    for (int off = 128; off > 0; off >>= 1) {
        if (t < off) sh[t] += sh[t + off];
        __syncthreads();
    }
    if (t == 0) bsum[blockIdx.x] = sh[0];
}

__global__ __launch_bounds__(1024) void scan_p2(int* __restrict__ bsum, int nb,
                                                int* __restrict__ total_out) {
    __shared__ int sh[1024];
    const int t = threadIdx.x;
    int v = (t < nb) ? bsum[t] : 0;
    sh[t] = v;
    __syncthreads();
    for (int off = 1; off < 1024; off <<= 1) {
        int add = (t >= off) ? sh[t - off] : 0;
        __syncthreads();
        sh[t] += add;
        __syncthreads();
    }
    if (t < nb) bsum[t] = sh[t] - v;  // exclusive
    if (t == 1023) *total_out = sh[1023];
}

__global__ __launch_bounds__(256) void scan_p3(const int* __restrict__ cnt, int n,
                                               const int* __restrict__ bsum,
                                               int* __restrict__ rowptr) {
    __shared__ int sh[256];
    const int t = threadIdx.x;
    const int base = blockIdx.x * 1024 + t * 4;
    int v[4];
    int s = 0;
#pragma unroll
    for (int i = 0; i < 4; i++) {
        int idx = base + i;
        v[i] = (idx < n) ? cnt[idx] : 0;
        s += v[i];
    }
    sh[t] = s;
    __syncthreads();
    const int mine = s;
    for (int off = 1; off < 256; off <<= 1) {
        int add = (t >= off) ? sh[t - off] : 0;
        __syncthreads();
        sh[t] += add;
        __syncthreads();
    }
    int run = bsum[blockIdx.x] + sh[t] - mine;
#pragma unroll
    for (int i = 0; i < 4; i++) {
        int idx = base + i;
        if (idx < n) rowptr[idx] = run;
        run += v[i];
    }
}

// ---------------------------------------------------------------------------
// mean aggregation: 32-lane group per dst row, bf16 in, f32 accumulate
// ---------------------------------------------------------------------------
template <bool OUT_F32>
__global__ __launch_bounds__(256) void agg_mean(const unsigned short* __restrict__ feat,
                                                const int* __restrict__ sorted,
                                                const int* __restrict__ rp, int n_dst,
                                                void* __restrict__ out) {
    const int g = blockIdx.x * 8 + (threadIdx.x >> 5);
    const int lane = threadIdx.x & 31;
    if (g >= n_dst) return;
    const int s = rp[g];
    const int e = rp[g + 1];
    float a0 = 0.f, a1 = 0.f, a2 = 0.f, a3 = 0.f;
    for (int j = s; j < e; ++j) {
        const int src = sorted[j];
        const ushort4 v = *(const ushort4*)&feat[(size_t)src * HDIM + (lane << 2)];
        a0 += bf2f(v.x); a1 += bf2f(v.y); a2 += bf2f(v.z); a3 += bf2f(v.w);
    }
    const float sc = (e > s) ? 1.0f / (float)(e - s) : 0.0f;
    a0 *= sc; a1 *= sc; a2 *= sc; a3 *= sc;
    if (OUT_F32) {
        float4 o; o.x = a0; o.y = a1; o.z = a2; o.w = a3;
        *(float4*)((float*)out + (size_t)g * HDIM + (lane << 2)) = o;
    } else {
        ushort4 o;
        o.x = f2bf(a0); o.y = f2bf(a1); o.z = f2bf(a2); o.w = f2bf(a3);
        *(ushort4*)((unsigned short*)out + (size_t)g * HDIM + (lane << 2)) = o;
    }
}

// ---------------------------------------------------------------------------
// bf16 MFMA GEMM, LDS-free.  out[r,c] = act( sum_m Xm[r,:]·Wm[c,:] + bias + add )
// Block: 256 thr = 4 waves, tile 64 rows x 128 cols; wave -> 16 rows x 128 cols.
// Fragments (mfma_f32_16x16x32_bf16): lane l, A: row=l&15, k=(l>>4)*8+j (16B run
// of row-major X); B: col=l&15, same k run of row-major W. C/D: col=l&15,
// row=(l>>4)*4+reg (m89-verified).
// ---------------------------------------------------------------------------
template <int K, int NMAT, bool HAS_ADD, bool ADD_F32, bool HAS_BIAS, bool LEAKY, bool OUT_F32>
__global__ __launch_bounds__(256) void gemm_mfma(
    const unsigned short* __restrict__ X1, const unsigned short* __restrict__ W1,
    const unsigned short* __restrict__ X2, const unsigned short* __restrict__ W2,
    const void* __restrict__ addv, const float* __restrict__ bias,
    void* __restrict__ out, int n) {
    const int lane = threadIdx.x & 63;
    const int w = threadIdx.x >> 6;            // wave 0..3
    const int fr = lane & 15;
    const int fq = lane >> 4;                  // 0..3
    const int rowbase = blockIdx.x * 64 + w * 16;

    f32x4 acc[8];
#pragma unroll
    for (int nn = 0; nn < 8; ++nn) acc[nn] = (f32x4){0.f, 0.f, 0.f, 0.f};

#pragma unroll
    for (int mat = 0; mat < NMAT; ++mat) {
        const unsigned short* __restrict__ X = (mat == 0) ? X1 : X2;
        const unsigned short* __restrict__ W = (mat == 0) ? W1 : W2;
        int ra = rowbase + fr;
        if (ra >= n) ra = n - 1;               // clamp (C-write guards real rows)
        const size_t xoff = (size_t)ra * K + fq * 8;
#pragma unroll 1
        for (int kb = 0; kb < K; kb += 32) {
            const bf16x8 a = *(const bf16x8*)(X + xoff + kb);
            bf16x8 b[8];
#pragma unroll
            for (int nn = 0; nn < 8; ++nn)
                b[nn] = *(const bf16x8*)(W + (size_t)(nn * 16 + fr) * K + kb + fq * 8);
#pragma unroll
            for (int nn = 0; nn < 8; ++nn)
                acc[nn] = __builtin_amdgcn_mfma_f32_16x16x32_bf16(a, b[nn], acc[nn], 0, 0, 0);
        }
    }

    // epilogue: lane covers rows rowbase+fq*4+0..3, cols nn*16+fr
    float bv[8];
#pragma unroll
    for (int nn = 0; nn < 8; ++nn) bv[nn] = HAS_BIAS ? bias[nn * 16 + fr] : 0.f;

#pragma unroll
    for (int j = 0; j < 4; ++j) {
        const int r = rowbase + fq * 4 + j;
        if (r < n) {
#pragma unroll
            for (int nn = 0; nn < 8; ++nn) {
                const int c = nn * 16 + fr;
                float v = acc[nn][j] + bv[nn];
                if (HAS_ADD) {
                    v += ADD_F32 ? ((const float*)addv)[(size_t)r * HDIM + c]
                                 : bf2f(((const unsigned short*)addv)[(size_t)r * HDIM + c]);
                }
                if (LEAKY) v = v > 0.f ? v : 0.1f * v;
                if (OUT_F32) ((float*)out)[(size_t)r * HDIM + c] = v;
                else ((unsigned short*)out)[(size_t)r * HDIM + c] = f2bf(v);
            }
        }
    }
}

// ---------------------------------------------------------------------------
extern "C" void kernel_launch(void* const* d_in, const int* in_sizes, int n_in,
                              void* d_out, int out_size, void* d_ws, size_t ws_size,
                              hipStream_t stream) {
    const float* genre    = (const float*)d_in[0];
    const float* user_emb = (const float*)d_in[1];
    const float* tag_emb  = (const float*)d_in[2];
    const float* movie_W  = (const float*)d_in[3];
    const float* movie_b  = (const float*)d_in[4];
    const float* Wn       = (const float*)d_in[5];
    const float* Wsf      = (const float*)d_in[6];
    const float* bsf      = (const float*)d_in[7];
    const int* rates_u    = (const int*)d_in[8];
    const int* rates_m    = (const int*)d_in[9];
    const int* tag_m      = (const int*)d_in[10];
    const int* tag_t      = (const int*)d_in[11];

    float* out_u = (float*)d_out;                 // NUSR x H (f32)
    float* out_m = out_u + (size_t)NUSR * HDIM;   // NMOV x H (f32)

    // ---- workspace carve-up ----
    char* w = (char*)d_ws;
    auto alloc = [&](size_t bytes) -> char* {
        char* p = w;
        w += (bytes + 511) & ~(size_t)511;
        return p;
    };
    unsigned short* ub  = (unsigned short*)alloc((size_t)NUSR * HDIM * 2);
    unsigned short* tb  = (unsigned short*)alloc((size_t)NTAG * HDIM * 2);
    unsigned short* gb  = (unsigned short*)alloc((size_t)NMOV * FDIM * 2);
    unsigned short* hm0 = (unsigned short*)alloc((size_t)NMOV * HDIM * 2);
    unsigned short* U1  = (unsigned short*)alloc((size_t)NUSR * HDIM * 2);
    unsigned short* M1  = (unsigned short*)alloc((size_t)NMOV * HDIM * 2);
    unsigned short* M2  = (unsigned short*)alloc((size_t)NMOV * HDIM * 2);
    unsigned short* M3  = (unsigned short*)alloc((size_t)NMOV * HDIM * 2);
    unsigned short* T1  = (unsigned short*)alloc((size_t)NTAG * HDIM * 2);
    unsigned short* T2  = (unsigned short*)alloc((size_t)NTAG * HDIM * 2);
    unsigned short* WB  = (unsigned short*)alloc((size_t)(8192 + 2 * 7 * WHH) * 2);
    float* bcc          = (float*)alloc(256 * 4);
    int* rowptr         = (int*)alloc((size_t)(NTOT + 1) * 4);
    int* sorted         = (int*)alloc((size_t)ETOT * 4);
    int* cur            = (int*)alloc((size_t)NTOT * 4);
    int* bsum           = (int*)alloc((size_t)1024 * 4);

    const unsigned short* WB_mW = WB;
    const unsigned short* WL0 = WB + 8192;
    const unsigned short* WL1 = WB + 8192 + 7 * WHH;

    // ---- feature/weight conversion ----
    cvt_bf16<<<cdiv(NUSR * HDIM / 4, 256), 256, 0, stream>>>(user_emb, ub, NUSR * HDIM / 4);
    cvt_bf16<<<cdiv(NTAG * HDIM / 4, 256), 256, 0, stream>>>(tag_emb, tb, NTAG * HDIM / 4);
    cvt_bf16<<<cdiv(NMOV * FDIM / 4, 256), 256, 0, stream>>>(genre, gb, NMOV * FDIM / 4);
    prep_weights<<<cdiv(8192 + 2 * 7 * WHH, 256), 256, 0, stream>>>(movie_W, Wn, Wsf, bsf, WB, bcc);

    // ---- fused CSR build ----
    hipMemsetAsync(cur, 0, (size_t)NTOT * 4, stream);
    hist_all<<<cdiv(ETOT, 256), 256, 0, stream>>>(rates_u, rates_m, tag_m, tag_t, cur);
    const int nb = cdiv(NTOT, 1024);
    scan_p1<<<nb, 256, 0, stream>>>(cur, NTOT, bsum);
    scan_p2<<<1, 1024, 0, stream>>>(bsum, nb, rowptr + NTOT);
    scan_p3<<<nb, 256, 0, stream>>>(cur, NTOT, bsum, rowptr);
    hipMemcpyAsync(cur, rowptr, (size_t)NTOT * 4, hipMemcpyDeviceToDevice, stream);
    scatter_all<<<cdiv(ETOT, 256), 256, 0, stream>>>(rates_u, rates_m, tag_m, tag_t, cur, sorted);

    const int GU = cdiv(NUSR, 64), GM = cdiv(NMOV, 64), GT = cdiv(NTAG, 64);

    // hm0 = genre @ movie_W.T + movie_b   (bf16 out)
    gemm_mfma<FDIM, 1, false, false, true, false, false><<<GM, 256, 0, stream>>>(
        gb, WB_mW, nullptr, nullptr, nullptr, movie_b, hm0, NMOV);

    // ================= layer 0 =================
    gemm_mfma<HDIM, 1, false, false, false, false, false><<<GM, 256, 0, stream>>>(
        hm0, WL0 + 1 * WHH, nullptr, nullptr, nullptr, nullptr, M3, NMOV);   // hm0 @ Wn[0,1].T
    gemm_mfma<HDIM, 1, false, false, false, false, false><<<GT, 256, 0, stream>>>(
        tb, WL0 + 3 * WHH, nullptr, nullptr, nullptr, nullptr, T1, NTAG);    // ht0 @ Wn[0,3].T
    agg_mean<false><<<cdiv(NUSR, 8), 256, 0, stream>>>(M3, sorted, rowptr + OFF_RU, NUSR, U1);
    agg_mean<false><<<cdiv(NMOV, 8), 256, 0, stream>>>(ub, sorted, rowptr + OFF_RM, NMOV, M1);
    agg_mean<false><<<cdiv(NMOV, 8), 256, 0, stream>>>(T1, sorted, rowptr + OFF_TM, NMOV, M2);
    agg_mean<false><<<cdiv(NTAG, 8), 256, 0, stream>>>(hm0, sorted, rowptr + OFF_TT, NTAG, T2);
    gemm_mfma<HDIM, 1, true, false, true, true, false><<<GU, 256, 0, stream>>>(
        ub, WL0 + 4 * WHH, nullptr, nullptr, U1, bsf + 1 * HDIM, U1, NUSR);          // hu1
    gemm_mfma<HDIM, 2, true, false, true, true, false><<<GM, 256, 0, stream>>>(
        hm0, WL0 + 6 * WHH, M1, WL0 + 0 * WHH, M2, bcc, M2, NMOV);                   // hm1
    gemm_mfma<HDIM, 2, false, false, true, true, false><<<GT, 256, 0, stream>>>(
        tb, WL0 + 5 * WHH, T2, WL0 + 2 * WHH, nullptr, bsf + 2 * HDIM, T2, NTAG);    // ht1

    // ================= layer 1 (tag update dead; outputs f32 -> d_out) =========
    gemm_mfma<HDIM, 1, false, false, false, false, false><<<GM, 256, 0, stream>>>(
        M2, WL1 + 1 * WHH, nullptr, nullptr, nullptr, nullptr, M3, NMOV);    // hm1 @ Wn[1,1].T
    gemm_mfma<HDIM, 1, false, false, false, false, false><<<GT, 256, 0, stream>>>(
        T2, WL1 + 3 * WHH, nullptr, nullptr, nullptr, nullptr, T1, NTAG);    // ht1 @ Wn[1,3].T
    agg_mean<true><<<cdiv(NUSR, 8), 256, 0, stream>>>(M3, sorted, rowptr + OFF_RU, NUSR, out_u);
    agg_mean<false><<<cdiv(NMOV, 8), 256, 0, stream>>>(U1, sorted, rowptr + OFF_RM, NMOV, M1);
    agg_mean<false><<<cdiv(NMOV, 8), 256, 0, stream>>>(T1, sorted, rowptr + OFF_TM, NMOV, hm0);
    gemm_mfma<HDIM, 1, true, true, true, true, true><<<GU, 256, 0, stream>>>(
        U1, WL1 + 4 * WHH, nullptr, nullptr, out_u, bsf + 5 * HDIM, out_u, NUSR);    // final hu
    gemm_mfma<HDIM, 2, true, false, true, true, true><<<GM, 256, 0, stream>>>(
        M2, WL1 + 6 * WHH, M1, WL1 + 0 * WHH, hm0, bcc + HDIM, out_m, NMOV);         // final hm
}

// Round 4
// 744.914 us; speedup vs baseline: 41.3308x; 1.3348x over previous
//
#include <hip/hip_runtime.h>
#include <stdint.h>

// ---------------------------------------------------------------------------
// HeteroGraphSAGE encoder, MI355X round 4.
// Round-3 post-mortem: scatter_all = 200us, WRITE_SIZE 154MB = 2.4M x 64B ->
// partial-line write amplification on random 4B stores. Fix: bucketized
// two-pass CSR build with LDS-staged grouping so every global write is a
// coalesced run. GEMM (LDS-free MFMA bf16) and aggregation unchanged.
// ---------------------------------------------------------------------------

#define NUSR 200000
#define NMOV 50000
#define NTAG 20000
#define FDIM 64
#define HDIM 128
#define NE1  800000
#define NE2  400000

#define OFF_RM 0
#define OFF_RU (NMOV)                        // 50000
#define OFF_TM (NMOV + NUSR)                 // 250000
#define OFF_TT (NMOV + NUSR + NMOV)          // 300000
#define NTOT   (2 * NMOV + NUSR + NTAG)      // 320000
#define ETOT   (2 * NE1 + 2 * NE2)           // 2.4M
#define WHH    (HDIM * HDIM)

// bucket layout: per-segment counter-width so mean edges/bucket ~= 4096
// seg0 rates->movies: 50000 ctr, CPB=256  -> 196 buckets (16 e/ctr)
// seg1 rates->users : 200000 ctr, CPB=1024 -> 196 buckets (4 e/ctr)
// seg2 tags ->movies: 50000 ctr, CPB=512  -> 98 buckets  (8 e/ctr)
// seg3 tags ->tags  : 20000 ctr, CPB=128  -> 157 buckets (20 e/ctr)
#define NB0 196
#define NB1 196
#define NB2 98
#define NB3 157
#define NB  (NB0 + NB1 + NB2 + NB3)          // 647
#define S1_EPB 8192
#define S1_B0 98                              // ceil(NE1/8192)
#define S1_B1 98
#define S1_B2 49                              // ceil(NE2/8192)
#define S1_B3 49
#define S1_NBLK (S1_B0 + S1_B1 + S1_B2 + S1_B3)  // 294
#define CAP 6144

typedef short bf16x8 __attribute__((ext_vector_type(8)));
typedef float f32x4 __attribute__((ext_vector_type(4)));

static inline int cdiv(int a, int b) { return (a + b - 1) / b; }

__device__ __forceinline__ float bf2f(unsigned short u) {
    union { unsigned int i; float f; } c;
    c.i = ((unsigned int)u) << 16;
    return c.f;
}
__device__ __forceinline__ unsigned short f2bf(float f) {
    union { float f; unsigned int i; } c;
    c.f = f;
    unsigned int i = c.i;
    return (unsigned short)((i + 0x7fffu + ((i >> 16) & 1u)) >> 16);  // RNE
}

// segment decode for the S1-style grid (294 blocks)
struct SegInfo {
    int e0, eN, sh, sbb, nb;
    const int* dstA;
    const int* srcA;
};
__device__ __forceinline__ SegInfo seg_decode(int blk, const int* ru, const int* rm,
                                              const int* tm, const int* tt) {
    SegInfo s;
    if (blk < S1_B0) {
        s.e0 = blk * S1_EPB; s.eN = NE1; s.sh = 8;  s.sbb = 0;                 s.nb = NB0;
        s.dstA = rm; s.srcA = ru;
    } else if (blk < S1_B0 + S1_B1) {
        s.e0 = (blk - S1_B0) * S1_EPB; s.eN = NE1; s.sh = 10; s.sbb = NB0;     s.nb = NB1;
        s.dstA = ru; s.srcA = rm;
    } else if (blk < S1_B0 + S1_B1 + S1_B2) {
        s.e0 = (blk - S1_B0 - S1_B1) * S1_EPB; s.eN = NE2; s.sh = 9;
        s.sbb = NB0 + NB1; s.nb = NB2;
        s.dstA = tm; s.srcA = tt;
    } else {
        s.e0 = (blk - S1_B0 - S1_B1 - S1_B2) * S1_EPB; s.eN = NE2; s.sh = 7;
        s.sbb = NB0 + NB1 + NB2; s.nb = NB3;
        s.dstA = tt; s.srcA = tm;
    }
    return s;
}

// ---------------------------------------------------------------------------
// CSR build, bucketized
// ---------------------------------------------------------------------------
__global__ __launch_bounds__(256) void csr_bucket_hist(const int* __restrict__ ru,
                                                       const int* __restrict__ rm,
                                                       const int* __restrict__ tm,
                                                       const int* __restrict__ tt,
                                                       int* __restrict__ bcnt) {
    __shared__ int h[256];
    const int t = threadIdx.x;
    h[t] = 0;
    __syncthreads();
    const SegInfo s = seg_decode(blockIdx.x, ru, rm, tm, tt);
#pragma unroll 4
    for (int i = 0; i < S1_EPB / 256; ++i) {
        const int e = s.e0 + t + i * 256;
        if (e < s.eN) atomicAdd(&h[s.dstA[e] >> s.sh], 1);
    }
    __syncthreads();
    if (t < s.nb) {
        const int c = h[t];
        if (c) atomicAdd(&bcnt[s.sbb + t], c);
    }
}

__global__ __launch_bounds__(1024) void csr_bscan(const int* __restrict__ bcnt,
                                                  int* __restrict__ bbase,
                                                  int* __restrict__ bcur,
                                                  int* __restrict__ rowptr) {
    __shared__ int sh[1024];
    const int t = threadIdx.x;
    const int v = (t < NB) ? bcnt[t] : 0;
    sh[t] = v;
    __syncthreads();
    for (int off = 1; off < 1024; off <<= 1) {
        const int add = (t >= off) ? sh[t - off] : 0;
        __syncthreads();
        sh[t] += add;
        __syncthreads();
    }
    const int ex = sh[t] - v;
    if (t < NB) { bbase[t] = ex; bcur[t] = ex; }
    if (t == NB - 1) bbase[NB] = ex + v;
    if (t == 0) rowptr[NTOT] = ETOT;
}

// S1: bin 8192 edges per block into buckets; coalesced grouped writes to tmp.
// record = (local_key << 18) | src   (local_key < 1024, src < 2^18)
__global__ __launch_bounds__(256) void csr_bin(const int* __restrict__ ru,
                                               const int* __restrict__ rm,
                                               const int* __restrict__ tm,
                                               const int* __restrict__ tt,
                                               int* __restrict__ bcur,
                                               int* __restrict__ tmp) {
    __shared__ int h[256], st[256], gb[256], cu[256];
    __shared__ int rec[S1_EPB];
    __shared__ unsigned short bk[S1_EPB];
    const int t = threadIdx.x;
    h[t] = 0;
    __syncthreads();
    const SegInfo s = seg_decode(blockIdx.x, ru, rm, tm, tt);
    const int mask = (1 << s.sh) - 1;
    // phase A: local bucket histogram
#pragma unroll 4
    for (int i = 0; i < S1_EPB / 256; ++i) {
        const int e = s.e0 + t + i * 256;
        if (e < s.eN) atomicAdd(&h[s.dstA[e] >> s.sh], 1);
    }
    __syncthreads();
    // phase B: scan -> local starts; reserve global space per bucket
    const int v = h[t];
    cu[t] = v;
    __syncthreads();
    for (int off = 1; off < 256; off <<= 1) {
        const int add = (t >= off) ? cu[t - off] : 0;
        __syncthreads();
        cu[t] += add;
        __syncthreads();
    }
    st[t] = cu[t] - v;
    gb[t] = (t < s.nb && v) ? atomicAdd(&bcur[s.sbb + t], v) : 0;
    cu[t] = st[t];
    __syncthreads();
    // phase C: re-read edges, place grouped in LDS
#pragma unroll 4
    for (int i = 0; i < S1_EPB / 256; ++i) {
        const int e = s.e0 + t + i * 256;
        if (e < s.eN) {
            const int d = s.dstA[e];
            const int lb = d >> s.sh;
            const int r = ((d & mask) << 18) | s.srcA[e];
            const int p = atomicAdd(&cu[lb], 1);
            rec[p] = r;
            bk[p] = (unsigned short)lb;
        }
    }
    __syncthreads();
    // phase D: coalesced write-out (runs of one bucket are contiguous)
    const int ecount = min(S1_EPB, s.eN - s.e0);
    for (int q = t; q < ecount; q += 256) {
        const int lb = bk[q];
        tmp[gb[lb] + (q - st[lb])] = rec[q];
    }
}

// S2: one block per bucket: counting-sort by counter, emit rowptr + sorted.
__global__ __launch_bounds__(256) void csr_sort(const int* __restrict__ tmp,
                                                const int* __restrict__ bbase,
                                                int* __restrict__ rowptr,
                                                int* __restrict__ sorted) {
    __shared__ int h[1024];
    __shared__ int part[256];
    __shared__ int outb[CAP];
    const int b = blockIdx.x;
    const int t = threadIdx.x;
    int c0, nctr;
    if (b < NB0)                 { c0 = OFF_RM + (b << 8);                nctr = min(256,  NMOV - (b << 8)); }
    else if (b < NB0 + NB1)      { const int j = b - NB0;                 c0 = OFF_RU + (j << 10); nctr = min(1024, NUSR - (j << 10)); }
    else if (b < NB0 + NB1 + NB2){ const int j = b - NB0 - NB1;           c0 = OFF_TM + (j << 9);  nctr = min(512,  NMOV - (j << 9)); }
    else                         { const int j = b - NB0 - NB1 - NB2;     c0 = OFF_TT + (j << 7);  nctr = min(128,  NTAG - (j << 7)); }
    for (int k = t; k < 1024; k += 256) h[k] = 0;
    __syncthreads();
    const int lo = bbase[b], hi = bbase[b + 1];
    const int n = hi - lo;
    for (int e = lo + t; e < hi; e += 256) atomicAdd(&h[tmp[e] >> 18], 1);
    __syncthreads();
    // exclusive scan over 1024 entries
    const int b4 = t * 4;
    const int a0 = h[b4], a1 = h[b4 + 1], a2 = h[b4 + 2], a3 = h[b4 + 3];
    const int sum = a0 + a1 + a2 + a3;
    part[t] = sum;
    __syncthreads();
    for (int off = 1; off < 256; off <<= 1) {
        const int add = (t >= off) ? part[t - off] : 0;
        __syncthreads();
        part[t] += add;
        __syncthreads();
    }
    int run = part[t] - sum;
    h[b4] = run; run += a0;
    h[b4 + 1] = run; run += a1;
    h[b4 + 2] = run; run += a2;
    h[b4 + 3] = run;
    __syncthreads();
    for (int k = t; k < nctr; k += 256) rowptr[c0 + k] = lo + h[k];
    __syncthreads();
    // h now = local exclusive starts, used as cursors
    if (n <= CAP) {
        for (int e = lo + t; e < hi; e += 256) {
            const int r = tmp[e];
            const int p = atomicAdd(&h[r >> 18], 1);
            outb[p] = r & 0x3FFFF;
        }
        __syncthreads();
        for (int q = t; q < n; q += 256) sorted[lo + q] = outb[q];
    } else {  // overflow fallback (statistically ~never: mean 4096, CAP 6144)
        for (int e = lo + t; e < hi; e += 256) {
            const int r = tmp[e];
            const int p = atomicAdd(&h[r >> 18], 1);
            sorted[lo + p] = r & 0x3FFFF;
        }
    }
}

// ---------------------------------------------------------------------------
// conversions / weight prep
// ---------------------------------------------------------------------------
__global__ __launch_bounds__(256) void cvt_bf16(const float* __restrict__ in,
                                                unsigned short* __restrict__ out, int n4) {
    int i = blockIdx.x * 256 + threadIdx.x;
    if (i < n4) {
        const float4 v = ((const float4*)in)[i];
        ushort4 o;
        o.x = f2bf(v.x); o.y = f2bf(v.y); o.z = f2bf(v.z); o.w = f2bf(v.w);
        ((ushort4*)out)[i] = o;
    }
}

// WB layout: [0,8192): movie_W.  Then per layer l (stride 7*WHH):
//   e=0..3: Wn[l,e]; e=4: Ws[l,1]; e=5: Ws[l,2]; e=6: Ws[l,0]+Ws[l,3].
// bcc[l*128+c] = bs[l,0,c]+bs[l,3,c].
__global__ __launch_bounds__(256) void prep_weights(const float* __restrict__ movie_W,
                                                    const float* __restrict__ Wn,
                                                    const float* __restrict__ Ws,
                                                    const float* __restrict__ bs,
                                                    unsigned short* __restrict__ WB,
                                                    float* __restrict__ bcc) {
    const int i = blockIdx.x * 256 + threadIdx.x;
    if (i < 256) {
        const int l = i >> 7, c = i & 127;
        bcc[i] = bs[(l * 4 + 0) * HDIM + c] + bs[(l * 4 + 3) * HDIM + c];
    }
    const int total = 8192 + 2 * 7 * WHH;
    if (i < total) {
        float v;
        if (i < 8192) {
            v = movie_W[i];
        } else {
            const int j = i - 8192;
            const int l = j / (7 * WHH);
            const int r = j % (7 * WHH);
            const int e = r / WHH;
            const int o = r % WHH;
            if (e < 4) v = Wn[(l * 4 + e) * WHH + o];
            else if (e == 4) v = Ws[(l * 4 + 1) * WHH + o];
            else if (e == 5) v = Ws[(l * 4 + 2) * WHH + o];
            else v = Ws[(l * 4 + 0) * WHH + o] + Ws[(l * 4 + 3) * WHH + o];
        }
        WB[i] = f2bf(v);
    }
}

// ---------------------------------------------------------------------------
// mean aggregation: 32-lane group per dst row, bf16 in, f32 accumulate
// ---------------------------------------------------------------------------
template <bool OUT_F32>
__global__ __launch_bounds__(256) void agg_mean(const unsigned short* __restrict__ feat,
                                                const int* __restrict__ sorted,
                                                const int* __restrict__ rp, int n_dst,
                                                void* __restrict__ out) {
    const int g = blockIdx.x * 8 + (threadIdx.x >> 5);
    const int lane = threadIdx.x & 31;
    if (g >= n_dst) return;
    const int s = rp[g];
    const int e = rp[g + 1];
    float a0 = 0.f, a1 = 0.f, a2 = 0.f, a3 = 0.f;
    for (int j = s; j < e; ++j) {
        const int src = sorted[j];
        const ushort4 v = *(const ushort4*)&feat[(size_t)src * HDIM + (lane << 2)];
        a0 += bf2f(v.x); a1 += bf2f(v.y); a2 += bf2f(v.z); a3 += bf2f(v.w);
    }
    const float sc = (e > s) ? 1.0f / (float)(e - s) : 0.0f;
    a0 *= sc; a1 *= sc; a2 *= sc; a3 *= sc;
    if (OUT_F32) {
        float4 o; o.x = a0; o.y = a1; o.z = a2; o.w = a3;
        *(float4*)((float*)out + (size_t)g * HDIM + (lane << 2)) = o;
    } else {
        ushort4 o;
        o.x = f2bf(a0); o.y = f2bf(a1); o.z = f2bf(a2); o.w = f2bf(a3);
        *(ushort4*)((unsigned short*)out + (size_t)g * HDIM + (lane << 2)) = o;
    }
}

// ---------------------------------------------------------------------------
// bf16 MFMA GEMM, LDS-free (round-3 design, verified).
// ---------------------------------------------------------------------------
template <int K, int NMAT, bool HAS_ADD, bool ADD_F32, bool HAS_BIAS, bool LEAKY, bool OUT_F32>
__global__ __launch_bounds__(256) void gemm_mfma(
    const unsigned short* __restrict__ X1, const unsigned short* __restrict__ W1,
    const unsigned short* __restrict__ X2, const unsigned short* __restrict__ W2,
    const void* __restrict__ addv, const float* __restrict__ bias,
    void* __restrict__ out, int n) {
    const int lane = threadIdx.x & 63;
    const int w = threadIdx.x >> 6;            // wave 0..3
    const int fr = lane & 15;
    const int fq = lane >> 4;                  // 0..3
    const int rowbase = blockIdx.x * 64 + w * 16;

    f32x4 acc[8];
#pragma unroll
    for (int nn = 0; nn < 8; ++nn) acc[nn] = (f32x4){0.f, 0.f, 0.f, 0.f};

#pragma unroll
    for (int mat = 0; mat < NMAT; ++mat) {
        const unsigned short* __restrict__ X = (mat == 0) ? X1 : X2;
        const unsigned short* __restrict__ W = (mat == 0) ? W1 : W2;
        int ra = rowbase + fr;
        if (ra >= n) ra = n - 1;               // clamp (C-write guards real rows)
        const size_t xoff = (size_t)ra * K + fq * 8;
#pragma unroll 1
        for (int kb = 0; kb < K; kb += 32) {
            const bf16x8 a = *(const bf16x8*)(X + xoff + kb);
            bf16x8 b[8];
#pragma unroll
            for (int nn = 0; nn < 8; ++nn)
                b[nn] = *(const bf16x8*)(W + (size_t)(nn * 16 + fr) * K + kb + fq * 8);
#pragma unroll
            for (int nn = 0; nn < 8; ++nn)
                acc[nn] = __builtin_amdgcn_mfma_f32_16x16x32_bf16(a, b[nn], acc[nn], 0, 0, 0);
        }
    }

    // epilogue: lane covers rows rowbase+fq*4+0..3, cols nn*16+fr
    float bv[8];
#pragma unroll
    for (int nn = 0; nn < 8; ++nn) bv[nn] = HAS_BIAS ? bias[nn * 16 + fr] : 0.f;

#pragma unroll
    for (int j = 0; j < 4; ++j) {
        const int r = rowbase + fq * 4 + j;
        if (r < n) {
#pragma unroll
            for (int nn = 0; nn < 8; ++nn) {
                const int c = nn * 16 + fr;
                float v = acc[nn][j] + bv[nn];
                if (HAS_ADD) {
                    v += ADD_F32 ? ((const float*)addv)[(size_t)r * HDIM + c]
                                 : bf2f(((const unsigned short*)addv)[(size_t)r * HDIM + c]);
                }
                if (LEAKY) v = v > 0.f ? v : 0.1f * v;
                if (OUT_F32) ((float*)out)[(size_t)r * HDIM + c] = v;
                else ((unsigned short*)out)[(size_t)r * HDIM + c] = f2bf(v);
            }
        }
    }
}

// ---------------------------------------------------------------------------
extern "C" void kernel_launch(void* const* d_in, const int* in_sizes, int n_in,
                              void* d_out, int out_size, void* d_ws, size_t ws_size,
                              hipStream_t stream) {
    const float* genre    = (const float*)d_in[0];
    const float* user_emb = (const float*)d_in[1];
    const float* tag_emb  = (const float*)d_in[2];
    const float* movie_W  = (const float*)d_in[3];
    const float* movie_b  = (const float*)d_in[4];
    const float* Wn       = (const float*)d_in[5];
    const float* Wsf      = (const float*)d_in[6];
    const float* bsf      = (const float*)d_in[7];
    const int* rates_u    = (const int*)d_in[8];
    const int* rates_m    = (const int*)d_in[9];
    const int* tag_m      = (const int*)d_in[10];
    const int* tag_t      = (const int*)d_in[11];

    float* out_u = (float*)d_out;                 // NUSR x H (f32)
    float* out_m = out_u + (size_t)NUSR * HDIM;   // NMOV x H (f32)

    // ---- workspace carve-up ----
    char* w = (char*)d_ws;
    auto alloc = [&](size_t bytes) -> char* {
        char* p = w;
        w += (bytes + 511) & ~(size_t)511;
        return p;
    };
    unsigned short* ub  = (unsigned short*)alloc((size_t)NUSR * HDIM * 2);
    unsigned short* tb  = (unsigned short*)alloc((size_t)NTAG * HDIM * 2);
    unsigned short* gb  = (unsigned short*)alloc((size_t)NMOV * FDIM * 2);
    unsigned short* hm0 = (unsigned short*)alloc((size_t)NMOV * HDIM * 2);
    unsigned short* U1  = (unsigned short*)alloc((size_t)NUSR * HDIM * 2);
    unsigned short* M1  = (unsigned short*)alloc((size_t)NMOV * HDIM * 2);
    unsigned short* M2  = (unsigned short*)alloc((size_t)NMOV * HDIM * 2);
    unsigned short* M3  = (unsigned short*)alloc((size_t)NMOV * HDIM * 2);
    unsigned short* T1  = (unsigned short*)alloc((size_t)NTAG * HDIM * 2);
    unsigned short* T2  = (unsigned short*)alloc((size_t)NTAG * HDIM * 2);
    unsigned short* WB  = (unsigned short*)alloc((size_t)(8192 + 2 * 7 * WHH) * 2);
    float* bcc          = (float*)alloc(256 * 4);
    int* rowptr         = (int*)alloc((size_t)(NTOT + 1) * 4);
    int* sorted         = (int*)alloc((size_t)ETOT * 4);
    int* tmpb           = (int*)alloc((size_t)ETOT * 4);
    int* bcnt           = (int*)alloc((size_t)(NB + 1) * 4);
    int* bbase          = (int*)alloc((size_t)(NB + 1) * 4);
    int* bcur           = (int*)alloc((size_t)(NB + 1) * 4);

    const unsigned short* WB_mW = WB;
    const unsigned short* WL0 = WB + 8192;
    const unsigned short* WL1 = WB + 8192 + 7 * WHH;

    // ---- feature/weight conversion ----
    cvt_bf16<<<cdiv(NUSR * HDIM / 4, 256), 256, 0, stream>>>(user_emb, ub, NUSR * HDIM / 4);
    cvt_bf16<<<cdiv(NTAG * HDIM / 4, 256), 256, 0, stream>>>(tag_emb, tb, NTAG * HDIM / 4);
    cvt_bf16<<<cdiv(NMOV * FDIM / 4, 256), 256, 0, stream>>>(genre, gb, NMOV * FDIM / 4);
    prep_weights<<<cdiv(8192 + 2 * 7 * WHH, 256), 256, 0, stream>>>(movie_W, Wn, Wsf, bsf, WB, bcc);

    // ---- bucketized CSR build ----
    hipMemsetAsync(bcnt, 0, (size_t)(NB + 1) * 4, stream);
    csr_bucket_hist<<<S1_NBLK, 256, 0, stream>>>(rates_u, rates_m, tag_m, tag_t, bcnt);
    csr_bscan<<<1, 1024, 0, stream>>>(bcnt, bbase, bcur, rowptr);
    csr_bin<<<S1_NBLK, 256, 0, stream>>>(rates_u, rates_m, tag_m, tag_t, bcur, tmpb);
    csr_sort<<<NB, 256, 0, stream>>>(tmpb, bbase, rowptr, sorted);

    const int GU = cdiv(NUSR, 64), GM = cdiv(NMOV, 64), GT = cdiv(NTAG, 64);

    // hm0 = genre @ movie_W.T + movie_b   (bf16 out)
    gemm_mfma<FDIM, 1, false, false, true, false, false><<<GM, 256, 0, stream>>>(
        gb, WB_mW, nullptr, nullptr, nullptr, movie_b, hm0, NMOV);

    // ================= layer 0 =================
    gemm_mfma<HDIM, 1, false, false, false, false, false><<<GM, 256, 0, stream>>>(
        hm0, WL0 + 1 * WHH, nullptr, nullptr, nullptr, nullptr, M3, NMOV);   // hm0 @ Wn[0,1].T
    gemm_mfma<HDIM, 1, false, false, false, false, false><<<GT, 256, 0, stream>>>(
        tb, WL0 + 3 * WHH, nullptr, nullptr, nullptr, nullptr, T1, NTAG);    // ht0 @ Wn[0,3].T
    agg_mean<false><<<cdiv(NUSR, 8), 256, 0, stream>>>(M3, sorted, rowptr + OFF_RU, NUSR, U1);
    agg_mean<false><<<cdiv(NMOV, 8), 256, 0, stream>>>(ub, sorted, rowptr + OFF_RM, NMOV, M1);
    agg_mean<false><<<cdiv(NMOV, 8), 256, 0, stream>>>(T1, sorted, rowptr + OFF_TM, NMOV, M2);
    agg_mean<false><<<cdiv(NTAG, 8), 256, 0, stream>>>(hm0, sorted, rowptr + OFF_TT, NTAG, T2);
    gemm_mfma<HDIM, 1, true, false, true, true, false><<<GU, 256, 0, stream>>>(
        ub, WL0 + 4 * WHH, nullptr, nullptr, U1, bsf + 1 * HDIM, U1, NUSR);          // hu1
    gemm_mfma<HDIM, 2, true, false, true, true, false><<<GM, 256, 0, stream>>>(
        hm0, WL0 + 6 * WHH, M1, WL0 + 0 * WHH, M2, bcc, M2, NMOV);                   // hm1
    gemm_mfma<HDIM, 2, false, false, true, true, false><<<GT, 256, 0, stream>>>(
        tb, WL0 + 5 * WHH, T2, WL0 + 2 * WHH, nullptr, bsf + 2 * HDIM, T2, NTAG);    // ht1

    // ================= layer 1 (tag update dead; outputs f32 -> d_out) =========
    gemm_mfma<HDIM, 1, false, false, false, false, false><<<GM, 256, 0, stream>>>(
        M2, WL1 + 1 * WHH, nullptr, nullptr, nullptr, nullptr, M3, NMOV);    // hm1 @ Wn[1,1].T
    gemm_mfma<HDIM, 1, false, false, false, false, false><<<GT, 256, 0, stream>>>(
        T2, WL1 + 3 * WHH, nullptr, nullptr, nullptr, nullptr, T1, NTAG);    // ht1 @ Wn[1,3].T
    agg_mean<true><<<cdiv(NUSR, 8), 256, 0, stream>>>(M3, sorted, rowptr + OFF_RU, NUSR, out_u);
    agg_mean<false><<<cdiv(NMOV, 8), 256, 0, stream>>>(U1, sorted, rowptr + OFF_RM, NMOV, M1);
    agg_mean<false><<<cdiv(NMOV, 8), 256, 0, stream>>>(T1, sorted, rowptr + OFF_TM, NMOV, hm0);
    gemm_mfma<HDIM, 1, true, true, true, true, true><<<GU, 256, 0, stream>>>(
        U1, WL1 + 4 * WHH, nullptr, nullptr, out_u, bsf + 5 * HDIM, out_u, NUSR);    // final hu
    gemm_mfma<HDIM, 2, true, false, true, true, true><<<GM, 256, 0, stream>>>(
        M2, WL1 + 6 * WHH, M1, WL1 + 0 * WHH, hm0, bcc + HDIM, out_m, NMOV);         // final hm
}

// Round 5
// 540.977 us; speedup vs baseline: 56.9117x; 1.3770x over previous
//
#include <hip/hip_runtime.h>
#include <stdint.h>

// ---------------------------------------------------------------------------
// HeteroGraphSAGE encoder, MI355X round 5.
// Round-4 post-mortem: final user GEMM 80us @2.2TB/s, latency-bound (1 row
// tile/wave), plus a 102MB f32 agg->GEMM round-trip. This round:
//   - all agg outputs bf16 (L1 user agg reuses the dead `ub` buffer)
//   - GEMM: 2 row-tiles per wave (128 rows/block) for 2x MLP
//   - launch fusion: cvt3, per-layer {pre2, agg4, update(fat runtime-seg)}
// CSR build (bucketized, coalesced) unchanged from round 4.
// ---------------------------------------------------------------------------

#define NUSR 200000
#define NMOV 50000
#define NTAG 20000
#define FDIM 64
#define HDIM 128
#define NE1  800000
#define NE2  400000

#define OFF_RM 0
#define OFF_RU (NMOV)
#define OFF_TM (NMOV + NUSR)
#define OFF_TT (NMOV + NUSR + NMOV)
#define NTOT   (2 * NMOV + NUSR + NTAG)      // 320000
#define ETOT   (2 * NE1 + 2 * NE2)           // 2.4M
#define WHH    (HDIM * HDIM)

// bucket layout (round 4): mean ~4096 edges/bucket
#define NB0 196
#define NB1 196
#define NB2 98
#define NB3 157
#define NB  (NB0 + NB1 + NB2 + NB3)          // 647
#define S1_EPB 8192
#define S1_B0 98
#define S1_B1 98
#define S1_B2 49
#define S1_B3 49
#define S1_NBLK (S1_B0 + S1_B1 + S1_B2 + S1_B3)  // 294
#define CAP 6144

typedef short bf16x8 __attribute__((ext_vector_type(8)));
typedef float f32x4 __attribute__((ext_vector_type(4)));

static inline int cdiv(int a, int b) { return (a + b - 1) / b; }

__device__ __forceinline__ float bf2f(unsigned short u) {
    union { unsigned int i; float f; } c;
    c.i = ((unsigned int)u) << 16;
    return c.f;
}
__device__ __forceinline__ unsigned short f2bf(float f) {
    union { float f; unsigned int i; } c;
    c.f = f;
    unsigned int i = c.i;
    return (unsigned short)((i + 0x7fffu + ((i >> 16) & 1u)) >> 16);  // RNE
}

// ---------------------------------------------------------------------------
// CSR build (round-4 bucketized design, unchanged)
// ---------------------------------------------------------------------------
struct SegInfo {
    int e0, eN, sh, sbb, nb;
    const int* dstA;
    const int* srcA;
};
__device__ __forceinline__ SegInfo seg_decode(int blk, const int* ru, const int* rm,
                                              const int* tm, const int* tt) {
    SegInfo s;
    if (blk < S1_B0) {
        s.e0 = blk * S1_EPB; s.eN = NE1; s.sh = 8;  s.sbb = 0;                 s.nb = NB0;
        s.dstA = rm; s.srcA = ru;
    } else if (blk < S1_B0 + S1_B1) {
        s.e0 = (blk - S1_B0) * S1_EPB; s.eN = NE1; s.sh = 10; s.sbb = NB0;     s.nb = NB1;
        s.dstA = ru; s.srcA = rm;
    } else if (blk < S1_B0 + S1_B1 + S1_B2) {
        s.e0 = (blk - S1_B0 - S1_B1) * S1_EPB; s.eN = NE2; s.sh = 9;
        s.sbb = NB0 + NB1; s.nb = NB2;
        s.dstA = tm; s.srcA = tt;
    } else {
        s.e0 = (blk - S1_B0 - S1_B1 - S1_B2) * S1_EPB; s.eN = NE2; s.sh = 7;
        s.sbb = NB0 + NB1 + NB2; s.nb = NB3;
        s.dstA = tt; s.srcA = tm;
    }
    return s;
}

__global__ __launch_bounds__(256) void csr_bucket_hist(const int* __restrict__ ru,
                                                       const int* __restrict__ rm,
                                                       const int* __restrict__ tm,
                                                       const int* __restrict__ tt,
                                                       int* __restrict__ bcnt) {
    __shared__ int h[256];
    const int t = threadIdx.x;
    h[t] = 0;
    __syncthreads();
    const SegInfo s = seg_decode(blockIdx.x, ru, rm, tm, tt);
#pragma unroll 4
    for (int i = 0; i < S1_EPB / 256; ++i) {
        const int e = s.e0 + t + i * 256;
        if (e < s.eN) atomicAdd(&h[s.dstA[e] >> s.sh], 1);
    }
    __syncthreads();
    if (t < s.nb) {
        const int c = h[t];
        if (c) atomicAdd(&bcnt[s.sbb + t], c);
    }
}

__global__ __launch_bounds__(1024) void csr_bscan(const int* __restrict__ bcnt,
                                                  int* __restrict__ bbase,
                                                  int* __restrict__ bcur,
                                                  int* __restrict__ rowptr) {
    __shared__ int sh[1024];
    const int t = threadIdx.x;
    const int v = (t < NB) ? bcnt[t] : 0;
    sh[t] = v;
    __syncthreads();
    for (int off = 1; off < 1024; off <<= 1) {
        const int add = (t >= off) ? sh[t - off] : 0;
        __syncthreads();
        sh[t] += add;
        __syncthreads();
    }
    const int ex = sh[t] - v;
    if (t < NB) { bbase[t] = ex; bcur[t] = ex; }
    if (t == NB - 1) bbase[NB] = ex + v;
    if (t == 0) rowptr[NTOT] = ETOT;
}

__global__ __launch_bounds__(256) void csr_bin(const int* __restrict__ ru,
                                               const int* __restrict__ rm,
                                               const int* __restrict__ tm,
                                               const int* __restrict__ tt,
                                               int* __restrict__ bcur,
                                               int* __restrict__ tmp) {
    __shared__ int h[256], st[256], gb[256], cu[256];
    __shared__ int rec[S1_EPB];
    __shared__ unsigned short bk[S1_EPB];
    const int t = threadIdx.x;
    h[t] = 0;
    __syncthreads();
    const SegInfo s = seg_decode(blockIdx.x, ru, rm, tm, tt);
    const int mask = (1 << s.sh) - 1;
#pragma unroll 4
    for (int i = 0; i < S1_EPB / 256; ++i) {
        const int e = s.e0 + t + i * 256;
        if (e < s.eN) atomicAdd(&h[s.dstA[e] >> s.sh], 1);
    }
    __syncthreads();
    const int v = h[t];
    cu[t] = v;
    __syncthreads();
    for (int off = 1; off < 256; off <<= 1) {
        const int add = (t >= off) ? cu[t - off] : 0;
        __syncthreads();
        cu[t] += add;
        __syncthreads();
    }
    st[t] = cu[t] - v;
    gb[t] = (t < s.nb && v) ? atomicAdd(&bcur[s.sbb + t], v) : 0;
    cu[t] = st[t];
    __syncthreads();
#pragma unroll 4
    for (int i = 0; i < S1_EPB / 256; ++i) {
        const int e = s.e0 + t + i * 256;
        if (e < s.eN) {
            const int d = s.dstA[e];
            const int lb = d >> s.sh;
            const int r = ((d & mask) << 18) | s.srcA[e];
            const int p = atomicAdd(&cu[lb], 1);
            rec[p] = r;
            bk[p] = (unsigned short)lb;
        }
    }
    __syncthreads();
    const int ecount = min(S1_EPB, s.eN - s.e0);
    for (int q = t; q < ecount; q += 256) {
        const int lb = bk[q];
        tmp[gb[lb] + (q - st[lb])] = rec[q];
    }
}

__global__ __launch_bounds__(256) void csr_sort(const int* __restrict__ tmp,
                                                const int* __restrict__ bbase,
                                                int* __restrict__ rowptr,
                                                int* __restrict__ sorted) {
    __shared__ int h[1024];
    __shared__ int part[256];
    __shared__ int outb[CAP];
    const int b = blockIdx.x;
    const int t = threadIdx.x;
    int c0, nctr;
    if (b < NB0)                 { c0 = OFF_RM + (b << 8);                nctr = min(256,  NMOV - (b << 8)); }
    else if (b < NB0 + NB1)      { const int j = b - NB0;                 c0 = OFF_RU + (j << 10); nctr = min(1024, NUSR - (j << 10)); }
    else if (b < NB0 + NB1 + NB2){ const int j = b - NB0 - NB1;           c0 = OFF_TM + (j << 9);  nctr = min(512,  NMOV - (j << 9)); }
    else                         { const int j = b - NB0 - NB1 - NB2;     c0 = OFF_TT + (j << 7);  nctr = min(128,  NTAG - (j << 7)); }
    for (int k = t; k < 1024; k += 256) h[k] = 0;
    __syncthreads();
    const int lo = bbase[b], hi = bbase[b + 1];
    const int n = hi - lo;
    for (int e = lo + t; e < hi; e += 256) atomicAdd(&h[tmp[e] >> 18], 1);
    __syncthreads();
    const int b4 = t * 4;
    const int a0 = h[b4], a1 = h[b4 + 1], a2 = h[b4 + 2], a3 = h[b4 + 3];
    const int sum = a0 + a1 + a2 + a3;
    part[t] = sum;
    __syncthreads();
    for (int off = 1; off < 256; off <<= 1) {
        const int add = (t >= off) ? part[t - off] : 0;
        __syncthreads();
        part[t] += add;
        __syncthreads();
    }
    int run = part[t] - sum;
    h[b4] = run; run += a0;
    h[b4 + 1] = run; run += a1;
    h[b4 + 2] = run; run += a2;
    h[b4 + 3] = run;
    __syncthreads();
    for (int k = t; k < nctr; k += 256) rowptr[c0 + k] = lo + h[k];
    __syncthreads();
    if (n <= CAP) {
        for (int e = lo + t; e < hi; e += 256) {
            const int r = tmp[e];
            const int p = atomicAdd(&h[r >> 18], 1);
            outb[p] = r & 0x3FFFF;
        }
        __syncthreads();
        for (int q = t; q < n; q += 256) sorted[lo + q] = outb[q];
    } else {
        for (int e = lo + t; e < hi; e += 256) {
            const int r = tmp[e];
            const int p = atomicAdd(&h[r >> 18], 1);
            sorted[lo + p] = r & 0x3FFFF;
        }
    }
}

// ---------------------------------------------------------------------------
// merged f32->bf16 conversion (user_emb, tag_emb, genre in one launch)
// ---------------------------------------------------------------------------
__global__ __launch_bounds__(256) void cvt3(const float* __restrict__ i0, unsigned short* __restrict__ o0, int n0,
                                            const float* __restrict__ i1, unsigned short* __restrict__ o1, int n1,
                                            const float* __restrict__ i2, unsigned short* __restrict__ o2, int n2) {
    int i = blockIdx.x * 256 + threadIdx.x;
    const float* in; unsigned short* out;
    if (i < n0) { in = i0; out = o0; }
    else if (i < n0 + n1) { in = i1; out = o1; i -= n0; }
    else if (i < n0 + n1 + n2) { in = i2; out = o2; i -= n0 + n1; }
    else return;
    const float4 v = ((const float4*)in)[i];
    ushort4 o;
    o.x = f2bf(v.x); o.y = f2bf(v.y); o.z = f2bf(v.z); o.w = f2bf(v.w);
    ((ushort4*)out)[i] = o;
}

// WB layout: [0,8192): movie_W.  Then per layer l (stride 7*WHH):
//   e=0..3: Wn[l,e]; e=4: Ws[l,1]; e=5: Ws[l,2]; e=6: Ws[l,0]+Ws[l,3].
__global__ __launch_bounds__(256) void prep_weights(const float* __restrict__ movie_W,
                                                    const float* __restrict__ Wn,
                                                    const float* __restrict__ Ws,
                                                    const float* __restrict__ bs,
                                                    unsigned short* __restrict__ WB,
                                                    float* __restrict__ bcc) {
    const int i = blockIdx.x * 256 + threadIdx.x;
    if (i < 256) {
        const int l = i >> 7, c = i & 127;
        bcc[i] = bs[(l * 4 + 0) * HDIM + c] + bs[(l * 4 + 3) * HDIM + c];
    }
    const int total = 8192 + 2 * 7 * WHH;
    if (i < total) {
        float v;
        if (i < 8192) {
            v = movie_W[i];
        } else {
            const int j = i - 8192;
            const int l = j / (7 * WHH);
            const int r = j % (7 * WHH);
            const int e = r / WHH;
            const int o = r % WHH;
            if (e < 4) v = Wn[(l * 4 + e) * WHH + o];
            else if (e == 4) v = Ws[(l * 4 + 1) * WHH + o];
            else if (e == 5) v = Ws[(l * 4 + 2) * WHH + o];
            else v = Ws[(l * 4 + 0) * WHH + o] + Ws[(l * 4 + 3) * WHH + o];
        }
        WB[i] = f2bf(v);
    }
}

// ---------------------------------------------------------------------------
// merged mean aggregation: up to 4 segments per launch, 16-lane groups,
// 16B/lane gathers, bf16 out everywhere, 2-edge unroll.
// ---------------------------------------------------------------------------
__global__ __launch_bounds__(256) void agg4(
    const unsigned short* __restrict__ f0, const int* __restrict__ rp0, unsigned short* __restrict__ o0,
    const unsigned short* __restrict__ f1, const int* __restrict__ rp1, unsigned short* __restrict__ o1,
    const unsigned short* __restrict__ f2, const int* __restrict__ rp2, unsigned short* __restrict__ o2,
    const unsigned short* __restrict__ f3, const int* __restrict__ rp3, unsigned short* __restrict__ o3,
    int c0, int c1, int c2, int c3,
    const int* __restrict__ sorted) {
    int g = blockIdx.x * 16 + (threadIdx.x >> 4);
    const unsigned short* feat; const int* rp; unsigned short* out;
    if (g < c0) { feat = f0; rp = rp0; out = o0; }
    else if (g < c1) { feat = f1; rp = rp1; out = o1; g -= c0; }
    else if (g < c2) { feat = f2; rp = rp2; out = o2; g -= c1; }
    else if (g < c3) { feat = f3; rp = rp3; out = o3; g -= c2; }
    else return;
    const int lane = threadIdx.x & 15;
    const int s = rp[g], e = rp[g + 1];
    float a[8];
#pragma unroll
    for (int k = 0; k < 8; ++k) a[k] = 0.f;
    int j = s;
    for (; j + 1 < e; j += 2) {
        const int s0 = sorted[j], s1 = sorted[j + 1];
        const bf16x8 v0 = *(const bf16x8*)&feat[(size_t)s0 * HDIM + lane * 8];
        const bf16x8 v1 = *(const bf16x8*)&feat[(size_t)s1 * HDIM + lane * 8];
#pragma unroll
        for (int k = 0; k < 8; ++k) a[k] += bf2f((unsigned short)v0[k]) + bf2f((unsigned short)v1[k]);
    }
    if (j < e) {
        const int s0 = sorted[j];
        const bf16x8 v0 = *(const bf16x8*)&feat[(size_t)s0 * HDIM + lane * 8];
#pragma unroll
        for (int k = 0; k < 8; ++k) a[k] += bf2f((unsigned short)v0[k]);
    }
    const float sc = (e > s) ? 1.0f / (float)(e - s) : 0.0f;
    bf16x8 o;
#pragma unroll
    for (int k = 0; k < 8; ++k) o[k] = (short)f2bf(a[k] * sc);
    *(bf16x8*)&out[(size_t)g * HDIM + lane * 8] = o;
}

// ---------------------------------------------------------------------------
// MFMA GEMM core: 2 row-tiles per wave, 128 rows/block, runtime flags.
// out[r,c] = act( sum_m Xm[r,:]·Wm[c,:] + bias[c] + add[r,c] )
// ---------------------------------------------------------------------------
template <int K>
__device__ __forceinline__ void gemm_core(
    const unsigned short* __restrict__ X1, const unsigned short* __restrict__ W1,
    const unsigned short* __restrict__ X2, const unsigned short* __restrict__ W2,
    const unsigned short* __restrict__ addv, const float* __restrict__ bias,
    void* __restrict__ out, int n, int out_f32, int leaky, int blk) {
    const int lane = threadIdx.x & 63;
    const int w = threadIdx.x >> 6;
    const int fr = lane & 15;
    const int fq = lane >> 4;
    const int wrow0 = blk * 128 + w * 32;

    f32x4 acc[2][8];
#pragma unroll
    for (int t = 0; t < 2; ++t)
#pragma unroll
        for (int nn = 0; nn < 8; ++nn) acc[t][nn] = (f32x4){0.f, 0.f, 0.f, 0.f};

    const int nmat = X2 ? 2 : 1;
#pragma unroll 1
    for (int mat = 0; mat < nmat; ++mat) {
        const unsigned short* __restrict__ X = mat ? X2 : X1;
        const unsigned short* __restrict__ W = mat ? W2 : W1;
        int ra0 = wrow0 + fr;        if (ra0 >= n) ra0 = n - 1;
        int ra1 = wrow0 + 16 + fr;   if (ra1 >= n) ra1 = n - 1;
        const size_t xo0 = (size_t)ra0 * K + fq * 8;
        const size_t xo1 = (size_t)ra1 * K + fq * 8;
#pragma unroll 1
        for (int kb = 0; kb < K; kb += 32) {
            const bf16x8 a0 = *(const bf16x8*)(X + xo0 + kb);
            const bf16x8 a1 = *(const bf16x8*)(X + xo1 + kb);
#pragma unroll
            for (int nn = 0; nn < 8; ++nn) {
                const bf16x8 b = *(const bf16x8*)(W + (size_t)(nn * 16 + fr) * K + kb + fq * 8);
                acc[0][nn] = __builtin_amdgcn_mfma_f32_16x16x32_bf16(a0, b, acc[0][nn], 0, 0, 0);
                acc[1][nn] = __builtin_amdgcn_mfma_f32_16x16x32_bf16(a1, b, acc[1][nn], 0, 0, 0);
            }
        }
    }

    float bv[8];
#pragma unroll
    for (int nn = 0; nn < 8; ++nn) bv[nn] = bias ? bias[nn * 16 + fr] : 0.f;

#pragma unroll
    for (int t = 0; t < 2; ++t) {
#pragma unroll
        for (int j = 0; j < 4; ++j) {
            const int r = wrow0 + t * 16 + fq * 4 + j;
            if (r < n) {
#pragma unroll
                for (int nn = 0; nn < 8; ++nn) {
                    const int c = nn * 16 + fr;
                    float v = acc[t][nn][j] + bv[nn];
                    if (addv) v += bf2f(addv[(size_t)r * HDIM + c]);
                    if (leaky) v = v > 0.f ? v : 0.1f * v;
                    if (out_f32) ((float*)out)[(size_t)r * HDIM + c] = v;
                    else ((unsigned short*)out)[(size_t)r * HDIM + c] = f2bf(v);
                }
            }
        }
    }
}

// genre projection: single segment, K=64, f32 bias, bf16 out
__global__ __launch_bounds__(256) void gemm_genre(const unsigned short* __restrict__ X,
                                                  const unsigned short* __restrict__ W,
                                                  const float* __restrict__ bias,
                                                  unsigned short* __restrict__ out, int n) {
    gemm_core<FDIM>(X, W, nullptr, nullptr, nullptr, bias, out, n, 0, 0, blockIdx.x);
}

// two pre-transform GEMMs (movie + tag) in one launch
__global__ __launch_bounds__(256) void gemm_pre2(
    const unsigned short* __restrict__ Xa, const unsigned short* __restrict__ Wa,
    unsigned short* __restrict__ oa, int na, int nblka,
    const unsigned short* __restrict__ Xb, const unsigned short* __restrict__ Wb,
    unsigned short* __restrict__ ob, int nb) {
    const int b = blockIdx.x;
    if (b < nblka) gemm_core<HDIM>(Xa, Wa, nullptr, nullptr, nullptr, nullptr, oa, na, 0, 0, b);
    else           gemm_core<HDIM>(Xb, Wb, nullptr, nullptr, nullptr, nullptr, ob, nb, 0, 0, b - nblka);
}

// fat update kernel: up to 3 runtime segments (user / movie / tag)
struct USeg {
    const unsigned short* X1; const unsigned short* W1;
    const unsigned short* X2; const unsigned short* W2;
    const unsigned short* addv; const float* bias;
    void* out; int n; int nblk; int out_f32;
};

__global__ __launch_bounds__(256) void gemm_update(USeg s0, USeg s1, USeg s2) {
    int b = blockIdx.x;
    USeg s;
    if (b < s0.nblk) s = s0;
    else if (b < s0.nblk + s1.nblk) { s = s1; b -= s0.nblk; }
    else { s = s2; b -= s0.nblk + s1.nblk; }
    gemm_core<HDIM>(s.X1, s.W1, s.X2, s.W2, s.addv, s.bias, s.out, s.n, s.out_f32, 1, b);
}

// ---------------------------------------------------------------------------
extern "C" void kernel_launch(void* const* d_in, const int* in_sizes, int n_in,
                              void* d_out, int out_size, void* d_ws, size_t ws_size,
                              hipStream_t stream) {
    const float* genre    = (const float*)d_in[0];
    const float* user_emb = (const float*)d_in[1];
    const float* tag_emb  = (const float*)d_in[2];
    const float* movie_W  = (const float*)d_in[3];
    const float* movie_b  = (const float*)d_in[4];
    const float* Wn       = (const float*)d_in[5];
    const float* Wsf      = (const float*)d_in[6];
    const float* bsf      = (const float*)d_in[7];
    const int* rates_u    = (const int*)d_in[8];
    const int* rates_m    = (const int*)d_in[9];
    const int* tag_m      = (const int*)d_in[10];
    const int* tag_t      = (const int*)d_in[11];

    float* out_u = (float*)d_out;                 // NUSR x H (f32)
    float* out_m = out_u + (size_t)NUSR * HDIM;   // NMOV x H (f32)

    // ---- workspace carve-up ----
    char* w = (char*)d_ws;
    auto alloc = [&](size_t bytes) -> char* {
        char* p = w;
        w += (bytes + 511) & ~(size_t)511;
        return p;
    };
    unsigned short* ub  = (unsigned short*)alloc((size_t)NUSR * HDIM * 2);  // L0: bf16 user; L1: U2 scratch
    unsigned short* tb  = (unsigned short*)alloc((size_t)NTAG * HDIM * 2);
    unsigned short* gb  = (unsigned short*)alloc((size_t)NMOV * FDIM * 2);
    unsigned short* hm0 = (unsigned short*)alloc((size_t)NMOV * HDIM * 2);
    unsigned short* U1  = (unsigned short*)alloc((size_t)NUSR * HDIM * 2);
    unsigned short* M1  = (unsigned short*)alloc((size_t)NMOV * HDIM * 2);
    unsigned short* M2  = (unsigned short*)alloc((size_t)NMOV * HDIM * 2);
    unsigned short* M3  = (unsigned short*)alloc((size_t)NMOV * HDIM * 2);
    unsigned short* T1  = (unsigned short*)alloc((size_t)NTAG * HDIM * 2);
    unsigned short* T2  = (unsigned short*)alloc((size_t)NTAG * HDIM * 2);
    unsigned short* WB  = (unsigned short*)alloc((size_t)(8192 + 2 * 7 * WHH) * 2);
    float* bcc          = (float*)alloc(256 * 4);
    int* rowptr         = (int*)alloc((size_t)(NTOT + 1) * 4);
    int* sorted         = (int*)alloc((size_t)ETOT * 4);
    int* tmpb           = (int*)alloc((size_t)ETOT * 4);
    int* bcnt           = (int*)alloc((size_t)(NB + 1) * 4);
    int* bbase          = (int*)alloc((size_t)(NB + 1) * 4);
    int* bcur           = (int*)alloc((size_t)(NB + 1) * 4);

    const unsigned short* WB_mW = WB;
    const unsigned short* WL0 = WB + 8192;
    const unsigned short* WL1 = WB + 8192 + 7 * WHH;

    // ---- conversions + weight prep ----
    const int n0 = NUSR * HDIM / 4, n1 = NTAG * HDIM / 4, n2 = NMOV * FDIM / 4;
    cvt3<<<cdiv(n0 + n1 + n2, 256), 256, 0, stream>>>(user_emb, ub, n0, tag_emb, tb, n1, genre, gb, n2);
    prep_weights<<<cdiv(8192 + 2 * 7 * WHH, 256), 256, 0, stream>>>(movie_W, Wn, Wsf, bsf, WB, bcc);

    // ---- bucketized CSR build ----
    hipMemsetAsync(bcnt, 0, (size_t)(NB + 1) * 4, stream);
    csr_bucket_hist<<<S1_NBLK, 256, 0, stream>>>(rates_u, rates_m, tag_m, tag_t, bcnt);
    csr_bscan<<<1, 1024, 0, stream>>>(bcnt, bbase, bcur, rowptr);
    csr_bin<<<S1_NBLK, 256, 0, stream>>>(rates_u, rates_m, tag_m, tag_t, bcur, tmpb);
    csr_sort<<<NB, 256, 0, stream>>>(tmpb, bbase, rowptr, sorted);

    const int GU = cdiv(NUSR, 128), GM = cdiv(NMOV, 128), GT = cdiv(NTAG, 128);

    // hm0 = genre @ movie_W.T + movie_b
    gemm_genre<<<GM, 256, 0, stream>>>(gb, WB_mW, movie_b, hm0, NMOV);

    // ================= layer 0 =================
    gemm_pre2<<<GM + GT, 256, 0, stream>>>(hm0, WL0 + 1 * WHH, M3, NMOV, GM,
                                           tb, WL0 + 3 * WHH, T1, NTAG);
    agg4<<<cdiv(NTOT, 16), 256, 0, stream>>>(
        M3, rowptr + OFF_RU, U1,
        ub, rowptr + OFF_RM, M1,
        T1, rowptr + OFF_TM, M2,
        hm0, rowptr + OFF_TT, T2,
        NUSR, NUSR + NMOV, NUSR + 2 * NMOV, NTOT, sorted);
    {
        USeg su = {ub, WL0 + 4 * WHH, nullptr, nullptr, U1, bsf + 1 * HDIM, U1, NUSR, GU, 0};
        USeg sm = {hm0, WL0 + 6 * WHH, M1, WL0 + 0 * WHH, M2, bcc, M2, NMOV, GM, 0};
        USeg st = {tb, WL0 + 5 * WHH, T2, WL0 + 2 * WHH, nullptr, bsf + 2 * HDIM, T2, NTAG, GT, 0};
        gemm_update<<<GU + GM + GT, 256, 0, stream>>>(su, sm, st);
    }

    // ================= layer 1 (tag update dead; outputs f32 -> d_out) =========
    gemm_pre2<<<GM + GT, 256, 0, stream>>>(M2, WL1 + 1 * WHH, M3, NMOV, GM,
                                           T2, WL1 + 3 * WHH, T1, NTAG);
    agg4<<<cdiv(NUSR + 2 * NMOV, 16), 256, 0, stream>>>(
        M3, rowptr + OFF_RU, ub,        // user agg -> U2 (= dead ub buffer)
        U1, rowptr + OFF_RM, M1,
        T1, rowptr + OFF_TM, hm0,
        nullptr, nullptr, nullptr,
        NUSR, NUSR + NMOV, NUSR + 2 * NMOV, NUSR + 2 * NMOV, sorted);
    {
        USeg su = {U1, WL1 + 4 * WHH, nullptr, nullptr, ub, bsf + 5 * HDIM, out_u, NUSR, GU, 1};
        USeg sm = {M2, WL1 + 6 * WHH, M1, WL1 + 0 * WHH, hm0, bcc + HDIM, out_m, NMOV, GM, 1};
        USeg sz = {nullptr, nullptr, nullptr, nullptr, nullptr, nullptr, nullptr, 0, 0, 0};
        gemm_update<<<GU + GM, 256, 0, stream>>>(su, sm, sz);
    }
}